// Round 9
// baseline (141.425 us; speedup 1.0000x reference)
//
#include <hip/hip_runtime.h>
#include <stdint.h>

// Problem constants
#define B_  2
#define S_  2048
#define D_  1024
#define H_  16
#define HD_ 64
#define M_  (B_*S_)   // 4096 rows

typedef __attribute__((ext_vector_type(8)))  short bf16x8;   // 8 bf16 in 4 VGPRs
typedef __attribute__((ext_vector_type(4)))  float f32x4;
typedef __attribute__((ext_vector_type(16))) float f32x16;
typedef __attribute__((ext_vector_type(4)))  unsigned int u32x4;

// ---- helpers ----------------------------------------------------------------

__device__ __forceinline__ unsigned short f2bf(float f) {
    unsigned int u = __float_as_uint(f);
    unsigned int r = (u + 0x7fffu + ((u >> 16) & 1u)) >> 16;
    return (unsigned short)r;
}

__device__ __forceinline__ unsigned int cvt_pk_bf16(float lo, float hi) {
    unsigned int r;
    asm("v_cvt_pk_bf16_f32 %0, %1, %2" : "=v"(r) : "v"(lo), "v"(hi));
    return r;
}

__device__ __forceinline__ void gload_lds16(const void* g, void* l) {
    __builtin_amdgcn_global_load_lds(
        (const __attribute__((address_space(1))) unsigned int*)g,
        (__attribute__((address_space(3))) unsigned int*)l,
        16, 0, 0);
}

// ---- fused fp32 -> bf16 cast; Wq/Wk pre-scaled by sqrt(log2(e)/8) -----------

__global__ __launch_bounds__(256) void cast_all(
    const float* __restrict__ x,
    const float* __restrict__ wq, const float* __restrict__ wk,
    const float* __restrict__ wv, const float* __restrict__ wo,
    unsigned short* __restrict__ dst)
{
    int b = blockIdx.x;
    const float* src;
    size_t soff, doff;
    float sc = 1.0f;
    if (b < 2048) {
        src = x; soff = (size_t)b * 2048; doff = soff;
    } else {
        int r  = (b - 2048) >> 9;
        int lb = (b - 2048) & 511;
        src = (r == 0) ? wq : (r == 1) ? wk : (r == 2) ? wv : wo;
        if (r <= 1) sc = 0.4246609093670877f;   // sqrt(log2(e)/sqrt(64))
        soff = (size_t)lb * 2048;
        doff = (size_t)4194304 + (size_t)r * 1048576 + soff;
    }
    int idx = threadIdx.x * 8;
    float4 a = *reinterpret_cast<const float4*>(src + soff + idx);
    float4 c = *reinterpret_cast<const float4*>(src + soff + idx + 4);
    unsigned short t[8];
    t[0]=f2bf(a.x*sc); t[1]=f2bf(a.y*sc); t[2]=f2bf(a.z*sc); t[3]=f2bf(a.w*sc);
    t[4]=f2bf(c.x*sc); t[5]=f2bf(c.y*sc); t[6]=f2bf(c.z*sc); t[7]=f2bf(c.w*sc);
    *reinterpret_cast<uint4*>(dst + doff + idx) = *reinterpret_cast<const uint4*>(t);
}

// ---- bf16 GEMM, C[M,N] = A[M,K] * Bm[N,K]^T (+bias) -------------------------

template <bool BIAS, typename CT>
__global__ __launch_bounds__(256) void gemm_bt(
    const unsigned short* __restrict__ A,
    const unsigned short* __restrict__ Bm,
    CT* __restrict__ C,
    const float* __restrict__ bias,
    int M, int N, int K)
{
    constexpr int BK = 32;
    __shared__ unsigned short As[128 * BK];
    __shared__ unsigned short Bs[128 * BK];

    const int tid  = threadIdx.x;
    const int lane = tid & 63;
    const int wid  = tid >> 6;
    const int wr = wid >> 1, wc = wid & 1;
    const int l15 = lane & 15, lhi = lane >> 4;
    const int tm = blockIdx.y * 128, tn = blockIdx.x * 128;

    f32x4 acc[4][4] = {};

    const int srow = (lane >> 2);
    const int scol = (lane & 3) * 8;

    for (int k0 = 0; k0 < K; k0 += BK) {
        __syncthreads();
        #pragma unroll
        for (int i = 0; i < 2; ++i) {
            int chunk = wid * 2 + i;
            int row = chunk * 16 + srow;
            gload_lds16(A  + (size_t)(tm + row) * K + k0 + scol, (void*)(As + chunk * 512));
            gload_lds16(Bm + (size_t)(tn + row) * K + k0 + scol, (void*)(Bs + chunk * 512));
        }
        __syncthreads();

        bf16x8 af[4], bfr[4];
        #pragma unroll
        for (int i = 0; i < 4; ++i)
            af[i] = *reinterpret_cast<const bf16x8*>(As + (wr * 64 + i * 16 + l15) * BK + lhi * 8);
        #pragma unroll
        for (int j = 0; j < 4; ++j)
            bfr[j] = *reinterpret_cast<const bf16x8*>(Bs + (wc * 64 + j * 16 + l15) * BK + lhi * 8);
        #pragma unroll
        for (int i = 0; i < 4; ++i)
            #pragma unroll
            for (int j = 0; j < 4; ++j)
                acc[i][j] = __builtin_amdgcn_mfma_f32_16x16x32_bf16(af[i], bfr[j], acc[i][j], 0, 0, 0);
    }

    #pragma unroll
    for (int i = 0; i < 4; ++i) {
        #pragma unroll
        for (int j = 0; j < 4; ++j) {
            int col = tn + wc * 64 + j * 16 + l15;
            float bv = BIAS ? bias[col] : 0.0f;
            #pragma unroll
            for (int r = 0; r < 4; ++r) {
                int row = tm + wr * 64 + i * 16 + lhi * 4 + r;
                float v = acc[i][j][r] + bv;
                if constexpr (sizeof(CT) == 2) {
                    ((unsigned short*)C)[(size_t)row * N + col] = f2bf(v);
                } else {
                    ((float*)C)[(size_t)row * N + col] = v;
                }
            }
        }
    }
}

// ---- merged QKV projection: [4096][3072] = x @ [Wq;Wk;Wv]^T -----------------

__global__ __launch_bounds__(256) void gemm_qkv(
    const unsigned short* __restrict__ A,
    const unsigned short* __restrict__ Bm,
    unsigned short* __restrict__ Cqk,
    unsigned short* __restrict__ Vt)
{
    constexpr int BK = 32, K = 1024;
    __shared__ unsigned short As[128 * BK];
    __shared__ unsigned short Bs[128 * BK];

    const int tid  = threadIdx.x;
    const int lane = tid & 63;
    const int wid  = tid >> 6;
    const int wr = wid >> 1, wc = wid & 1;
    const int l15 = lane & 15, lhi = lane >> 4;
    const int tm = blockIdx.y * 128, tn = blockIdx.x * 128;

    f32x4 acc[4][4] = {};

    const int srow = (lane >> 2);
    const int scol = (lane & 3) * 8;

    for (int k0 = 0; k0 < K; k0 += BK) {
        __syncthreads();
        #pragma unroll
        for (int i = 0; i < 2; ++i) {
            int chunk = wid * 2 + i;
            int row = chunk * 16 + srow;
            gload_lds16(A  + (size_t)(tm + row) * K + k0 + scol, (void*)(As + chunk * 512));
            gload_lds16(Bm + (size_t)(tn + row) * K + k0 + scol, (void*)(Bs + chunk * 512));
        }
        __syncthreads();

        bf16x8 af[4], bfr[4];
        #pragma unroll
        for (int i = 0; i < 4; ++i)
            af[i] = *reinterpret_cast<const bf16x8*>(As + (wr * 64 + i * 16 + l15) * BK + lhi * 8);
        #pragma unroll
        for (int j = 0; j < 4; ++j)
            bfr[j] = *reinterpret_cast<const bf16x8*>(Bs + (wc * 64 + j * 16 + l15) * BK + lhi * 8);
        #pragma unroll
        for (int i = 0; i < 4; ++i)
            #pragma unroll
            for (int j = 0; j < 4; ++j)
                acc[i][j] = __builtin_amdgcn_mfma_f32_16x16x32_bf16(af[i], bfr[j], acc[i][j], 0, 0, 0);
    }

    const bool isV = (tn >= 2048);
    #pragma unroll
    for (int i = 0; i < 4; ++i) {
        #pragma unroll
        for (int j = 0; j < 4; ++j) {
            int col = tn + wc * 64 + j * 16 + l15;
            int row0 = tm + wr * 64 + i * 16 + lhi * 4;
            if (!isV) {
                #pragma unroll
                for (int r = 0; r < 4; ++r)
                    Cqk[(size_t)(row0 + r) * 2048 + col] = f2bf(acc[i][j][r]);
            } else {
                unsigned short t[4];
                #pragma unroll
                for (int r = 0; r < 4; ++r) t[r] = f2bf(acc[i][j][r]);
                *reinterpret_cast<uint2*>(Vt + (size_t)(col - 2048) * M_ + row0) =
                    *reinterpret_cast<const uint2*>(t);
            }
        }
    }
}

// ---- flash attention (causal), shared-KV 4-wave blocks ----------------------
// QK: [4096][2048] bf16 — Q cols 0..1023 (pre-scaled), K cols 1024..2047
// VT: [1024][4096] bf16 — row h*64+d, col b*2048+k
// grid 512 x 256: block owns 128 q rows (wave w -> q-tile 4*qsb+w); all waves
// consume the SAME causal KV prefix, so ONE shared double-buffered 32-kv tile
// (16 KB LDS total) serves all 4 waves; staging cooperative (2 gload_lds/wave).
// Per tile: {vmcnt(0) [fully covered]; barrier; STAGE(kt+1); compute(kt)}.
// Static softmax (bounded scores, exp2 domain); per-wave direct store.

__global__ __launch_bounds__(256) void attn_kernel(
    const unsigned short* __restrict__ QK,
    const unsigned short* __restrict__ VT,
    unsigned short* __restrict__ Ctx)
{
    __shared__ unsigned short Ks[2][32 * 64];   // [kv][d]  128B rows, swz ^(row&7)
    __shared__ unsigned short Vs[2][64 * 32];   // [d][kv]   64B rows, swz ^((d>>1)&3)

    const int tid  = threadIdx.x;
    const int lane = tid & 63;
    const int wid  = tid >> 6;          // 0..3
    const int l31  = lane & 31;
    const int hi   = lane >> 5;

    // XCD-aware remap (lin%8 = XCD); heavy q-super-blocks first
    const int lin  = blockIdx.x;        // 0..511
    const int xcd  = lin & 7;
    const int idx  = lin >> 3;          // 0..63
    const int bh   = xcd + 8 * (idx & 3);
    const int qsb  = 15 - (idx >> 2);   // 0..15, heavy first
    const int b = bh >> 4, h = bh & 15;
    const size_t baseRow = (size_t)b * S_;
    const int qw = qsb * 128 + wid * 32;   // wave's first q row
    const int q  = qw + l31;
    const int myKT = qw >> 5;              // wave's diagonal 32-tile
    const int nkt  = qsb * 4 + 4;          // tiles staged by the block

    // Q B-fragments (pre-scaled at cast time)
    bf16x8 qf[4];
    #pragma unroll
    for (int s = 0; s < 4; ++s)
        qf[s] = *reinterpret_cast<const bf16x8*>(
            QK + (baseRow + q) * 2048 + h * HD_ + s * 16 + hi * 8);

    float l = 0.0f;
    f32x16 oacc[2] = {};

    // cooperative staging: wave wid stages K rows wid*8+(lane>>3) and
    // V rows wid*16+(lane>>2) — 2 gload_lds per wave per tile.
    const int kr8  = lane >> 3;         // 0..7
    const int ksl  = lane & 7;
    const int vr16 = lane >> 2;         // 0..15
    const int vsl  = lane & 3;

#define STAGE(kt_, bi_) do {                                                   \
    int k0_ = (kt_) * 32;                                                      \
    int krow_ = wid * 8 + kr8;                                                 \
    int ksc_  = (ksl ^ kr8) * 8;                                               \
    gload_lds16(QK + (baseRow + k0_ + krow_) * 2048 + D_ + h * HD_ + ksc_,     \
                (void*)(&Ks[bi_][wid * 512]));                                 \
    int vrow_ = wid * 16 + vr16;                                               \
    int vsc_  = (vsl ^ ((vr16 >> 1) & 3)) * 8;                                 \
    gload_lds16(VT + (size_t)(h * HD_ + vrow_) * M_ + baseRow + k0_ + vsc_,    \
                (void*)(&Vs[bi_][wid * 512]));                                 \
    } while (0)

    STAGE(0, 0);

    for (int kt = 0; kt < nkt; ++kt) {
        const int cur = kt & 1;
        asm volatile("s_waitcnt vmcnt(0)" ::: "memory");   // my stage(kt) done (covered)
        __builtin_amdgcn_s_barrier();                      // all stages done; old buf free
        __builtin_amdgcn_sched_barrier(0);
        if (kt + 1 < nkt) STAGE(kt + 1, cur ^ 1);

        if (kt > myKT) continue;        // past diagonal: staging+barrier only

        const unsigned short* Kc = &Ks[cur][0];
        const unsigned short* Vc = &Vs[cur][0];

        // V B-fragments first (independent of scores)
        bf16x8 vf[2][2];
        #pragma unroll
        for (int dt = 0; dt < 2; ++dt)
            #pragma unroll
            for (int s = 0; s < 2; ++s) {
                int d = dt * 32 + l31;
                int sl = (2 * s + hi) ^ ((d >> 1) & 3);
                vf[dt][s] = *reinterpret_cast<const bf16x8*>(Vc + d * 32 + sl * 8);
            }

        // swapped QK^T: sc[row=kv local][col=q=l31]
        f32x16 sc = {};
        #pragma unroll
        for (int s = 0; s < 4; ++s) {
            int sl = (2 * s + hi) ^ (l31 & 7);
            bf16x8 kf = *reinterpret_cast<const bf16x8*>(Kc + l31 * 64 + sl * 8);
            sc = __builtin_amdgcn_mfma_f32_32x32x16_bf16(kf, qf[s], sc, 0, 0, 0);
        }

        if (kt == myKT) {   // diagonal tile: causal mask
            #pragma unroll
            for (int r = 0; r < 16; ++r) {
                int kl = kt * 32 + (r & 3) + 8 * (r >> 2) + 4 * hi;
                if (kl > q) sc[r] = -INFINITY;
            }
        }

        // static softmax (exp2 domain) -> packed bf16 P
        unsigned int g0, g1, g2, g3, g4, g5, g6, g7;
        float ps = 0.0f;
        {
            float e0, e1, e2, e3;
            e0=exp2f(sc[0]);  e1=exp2f(sc[1]);  e2=exp2f(sc[2]);  e3=exp2f(sc[3]);
            ps += (e0+e1)+(e2+e3); g0 = cvt_pk_bf16(e0,e1); g1 = cvt_pk_bf16(e2,e3);
            e0=exp2f(sc[4]);  e1=exp2f(sc[5]);  e2=exp2f(sc[6]);  e3=exp2f(sc[7]);
            ps += (e0+e1)+(e2+e3); g2 = cvt_pk_bf16(e0,e1); g3 = cvt_pk_bf16(e2,e3);
            e0=exp2f(sc[8]);  e1=exp2f(sc[9]);  e2=exp2f(sc[10]); e3=exp2f(sc[11]);
            ps += (e0+e1)+(e2+e3); g4 = cvt_pk_bf16(e0,e1); g5 = cvt_pk_bf16(e2,e3);
            e0=exp2f(sc[12]); e1=exp2f(sc[13]); e2=exp2f(sc[14]); e3=exp2f(sc[15]);
            ps += (e0+e1)+(e2+e3); g6 = cvt_pk_bf16(e0,e1); g7 = cvt_pk_bf16(e2,e3);
        }
        l += ps;   // cross-half combine deferred to epilogue

        // P -> A-fragments via permlane32_swap
        asm("v_permlane32_swap_b32 %0, %1" : "+v"(g0), "+v"(g2));
        asm("v_permlane32_swap_b32 %0, %1" : "+v"(g1), "+v"(g3));
        asm("v_permlane32_swap_b32 %0, %1" : "+v"(g4), "+v"(g6));
        asm("v_permlane32_swap_b32 %0, %1" : "+v"(g5), "+v"(g7));
        bf16x8 pa0 = __builtin_bit_cast(bf16x8, (u32x4){g0, g1, g2, g3});
        bf16x8 pa1 = __builtin_bit_cast(bf16x8, (u32x4){g4, g5, g6, g7});

        // O += P · V   (pure MFMA cluster)
        __builtin_amdgcn_s_setprio(1);
        #pragma unroll
        for (int dt = 0; dt < 2; ++dt) {
            oacc[dt] = __builtin_amdgcn_mfma_f32_32x32x16_bf16(pa0, vf[dt][0], oacc[dt], 0, 0, 0);
            oacc[dt] = __builtin_amdgcn_mfma_f32_32x32x16_bf16(pa1, vf[dt][1], oacc[dt], 0, 0, 0);
        }
        __builtin_amdgcn_s_setprio(0);
    }
#undef STAGE

    // epilogue: combine halves, normalize, store (per-wave rows)
    l += __shfl_xor(l, 32, 64);
    float inv = 1.0f / l;
    #pragma unroll
    for (int r = 0; r < 16; ++r) {
        int qr = (r & 3) + 8 * (r >> 2) + 4 * hi;
        float ir = __shfl(inv, qr, 32);
        #pragma unroll
        for (int dt = 0; dt < 2; ++dt)
            Ctx[(baseRow + qw + qr) * D_ + h * HD_ + dt * 32 + l31] =
                f2bf(oacc[dt][r] * ir);
    }
}

// ---- launch -----------------------------------------------------------------

extern "C" void kernel_launch(void* const* d_in, const int* in_sizes, int n_in,
                              void* d_out, int out_size, void* d_ws, size_t ws_size,
                              hipStream_t stream) {
    const float* x  = (const float*)d_in[0];
    const float* wq = (const float*)d_in[1];
    const float* wk = (const float*)d_in[2];
    const float* wv = (const float*)d_in[3];
    const float* wo = (const float*)d_in[4];
    const float* bo = (const float*)d_in[5];

    unsigned short* ws = (unsigned short*)d_ws;
    unsigned short* xb  = ws;                       // [4096][1024]  8 MB
    unsigned short* wqb = xb  + 4194304;            // wq|wk|wv stacked
    unsigned short* wob = wqb + 3145728;
    unsigned short* QKb = wob + 1048576;            // [4096][2048] 16 MB
    unsigned short* VT  = QKb + 8388608;            // [1024][4096]  8 MB
    unsigned short* Cx  = VT  + 4194304;            // [4096][1024]  8 MB

    cast_all<<<4096, 256, 0, stream>>>(x, wq, wk, wv, wo, xb);

    // merged QKV projection (V written transposed)
    gemm_qkv<<<dim3(24, 32), 256, 0, stream>>>(xb, wqb, QKb, VT);

    // causal flash attention, shared-KV 4-wave blocks
    attn_kernel<<<512, 256, 0, stream>>>(QKb, VT, Cx);

    // out = ctx @ Wo^T + b_out  (fp32 out)
    gemm_bt<true, float><<<dim3(8, 32), 256, 0, stream>>>(
        Cx, wob, (float*)d_out, bo, M_, D_, D_);
}

// Round 10
// 139.658 us; speedup vs baseline: 1.0126x; 1.0126x over previous
//
#include <hip/hip_runtime.h>
#include <stdint.h>

// Problem constants
#define B_  2
#define S_  2048
#define D_  1024
#define H_  16
#define HD_ 64
#define M_  (B_*S_)   // 4096 rows

typedef __attribute__((ext_vector_type(8)))  short bf16x8;   // 8 bf16 in 4 VGPRs
typedef __attribute__((ext_vector_type(4)))  float f32x4;
typedef __attribute__((ext_vector_type(16))) float f32x16;
typedef __attribute__((ext_vector_type(4)))  unsigned int u32x4;

// ---- helpers ----------------------------------------------------------------

__device__ __forceinline__ unsigned short f2bf(float f) {
    unsigned int u = __float_as_uint(f);
    unsigned int r = (u + 0x7fffu + ((u >> 16) & 1u)) >> 16;
    return (unsigned short)r;
}

__device__ __forceinline__ unsigned int cvt_pk_bf16(float lo, float hi) {
    unsigned int r;
    asm("v_cvt_pk_bf16_f32 %0, %1, %2" : "=v"(r) : "v"(lo), "v"(hi));
    return r;
}

__device__ __forceinline__ void gload_lds16(const void* g, void* l) {
    __builtin_amdgcn_global_load_lds(
        (const __attribute__((address_space(1))) unsigned int*)g,
        (__attribute__((address_space(3))) unsigned int*)l,
        16, 0, 0);
}

// ---- fused fp32 -> bf16 cast; Wq/Wk pre-scaled by sqrt(log2(e)/8) -----------

__global__ __launch_bounds__(256) void cast_all(
    const float* __restrict__ x,
    const float* __restrict__ wq, const float* __restrict__ wk,
    const float* __restrict__ wv, const float* __restrict__ wo,
    unsigned short* __restrict__ dst)
{
    int b = blockIdx.x;
    const float* src;
    size_t soff, doff;
    float sc = 1.0f;
    if (b < 2048) {
        src = x; soff = (size_t)b * 2048; doff = soff;
    } else {
        int r  = (b - 2048) >> 9;
        int lb = (b - 2048) & 511;
        src = (r == 0) ? wq : (r == 1) ? wk : (r == 2) ? wv : wo;
        if (r <= 1) sc = 0.4246609093670877f;   // sqrt(log2(e)/sqrt(64))
        soff = (size_t)lb * 2048;
        doff = (size_t)4194304 + (size_t)r * 1048576 + soff;
    }
    int idx = threadIdx.x * 8;
    float4 a = *reinterpret_cast<const float4*>(src + soff + idx);
    float4 c = *reinterpret_cast<const float4*>(src + soff + idx + 4);
    unsigned short t[8];
    t[0]=f2bf(a.x*sc); t[1]=f2bf(a.y*sc); t[2]=f2bf(a.z*sc); t[3]=f2bf(a.w*sc);
    t[4]=f2bf(c.x*sc); t[5]=f2bf(c.y*sc); t[6]=f2bf(c.z*sc); t[7]=f2bf(c.w*sc);
    *reinterpret_cast<uint4*>(dst + doff + idx) = *reinterpret_cast<const uint4*>(t);
}

// ---- bf16 GEMM, C[M,N] = A[M,K] * Bm[N,K]^T (+bias) -------------------------

template <bool BIAS, typename CT>
__global__ __launch_bounds__(256) void gemm_bt(
    const unsigned short* __restrict__ A,
    const unsigned short* __restrict__ Bm,
    CT* __restrict__ C,
    const float* __restrict__ bias,
    int M, int N, int K)
{
    constexpr int BK = 32;
    __shared__ unsigned short As[128 * BK];
    __shared__ unsigned short Bs[128 * BK];

    const int tid  = threadIdx.x;
    const int lane = tid & 63;
    const int wid  = tid >> 6;
    const int wr = wid >> 1, wc = wid & 1;
    const int l15 = lane & 15, lhi = lane >> 4;
    const int tm = blockIdx.y * 128, tn = blockIdx.x * 128;

    f32x4 acc[4][4] = {};

    const int srow = (lane >> 2);
    const int scol = (lane & 3) * 8;

    for (int k0 = 0; k0 < K; k0 += BK) {
        __syncthreads();
        #pragma unroll
        for (int i = 0; i < 2; ++i) {
            int chunk = wid * 2 + i;
            int row = chunk * 16 + srow;
            gload_lds16(A  + (size_t)(tm + row) * K + k0 + scol, (void*)(As + chunk * 512));
            gload_lds16(Bm + (size_t)(tn + row) * K + k0 + scol, (void*)(Bs + chunk * 512));
        }
        __syncthreads();

        bf16x8 af[4], bfr[4];
        #pragma unroll
        for (int i = 0; i < 4; ++i)
            af[i] = *reinterpret_cast<const bf16x8*>(As + (wr * 64 + i * 16 + l15) * BK + lhi * 8);
        #pragma unroll
        for (int j = 0; j < 4; ++j)
            bfr[j] = *reinterpret_cast<const bf16x8*>(Bs + (wc * 64 + j * 16 + l15) * BK + lhi * 8);
        #pragma unroll
        for (int i = 0; i < 4; ++i)
            #pragma unroll
            for (int j = 0; j < 4; ++j)
                acc[i][j] = __builtin_amdgcn_mfma_f32_16x16x32_bf16(af[i], bfr[j], acc[i][j], 0, 0, 0);
    }

    #pragma unroll
    for (int i = 0; i < 4; ++i) {
        #pragma unroll
        for (int j = 0; j < 4; ++j) {
            int col = tn + wc * 64 + j * 16 + l15;
            float bv = BIAS ? bias[col] : 0.0f;
            #pragma unroll
            for (int r = 0; r < 4; ++r) {
                int row = tm + wr * 64 + i * 16 + lhi * 4 + r;
                float v = acc[i][j][r] + bv;
                if constexpr (sizeof(CT) == 2) {
                    ((unsigned short*)C)[(size_t)row * N + col] = f2bf(v);
                } else {
                    ((float*)C)[(size_t)row * N + col] = v;
                }
            }
        }
    }
}

// ---- merged QKV projection: [4096][3072] = x @ [Wq;Wk;Wv]^T -----------------

__global__ __launch_bounds__(256) void gemm_qkv(
    const unsigned short* __restrict__ A,
    const unsigned short* __restrict__ Bm,
    unsigned short* __restrict__ Cqk,
    unsigned short* __restrict__ Vt)
{
    constexpr int BK = 32, K = 1024;
    __shared__ unsigned short As[128 * BK];
    __shared__ unsigned short Bs[128 * BK];

    const int tid  = threadIdx.x;
    const int lane = tid & 63;
    const int wid  = tid >> 6;
    const int wr = wid >> 1, wc = wid & 1;
    const int l15 = lane & 15, lhi = lane >> 4;
    const int tm = blockIdx.y * 128, tn = blockIdx.x * 128;

    f32x4 acc[4][4] = {};

    const int srow = (lane >> 2);
    const int scol = (lane & 3) * 8;

    for (int k0 = 0; k0 < K; k0 += BK) {
        __syncthreads();
        #pragma unroll
        for (int i = 0; i < 2; ++i) {
            int chunk = wid * 2 + i;
            int row = chunk * 16 + srow;
            gload_lds16(A  + (size_t)(tm + row) * K + k0 + scol, (void*)(As + chunk * 512));
            gload_lds16(Bm + (size_t)(tn + row) * K + k0 + scol, (void*)(Bs + chunk * 512));
        }
        __syncthreads();

        bf16x8 af[4], bfr[4];
        #pragma unroll
        for (int i = 0; i < 4; ++i)
            af[i] = *reinterpret_cast<const bf16x8*>(As + (wr * 64 + i * 16 + l15) * BK + lhi * 8);
        #pragma unroll
        for (int j = 0; j < 4; ++j)
            bfr[j] = *reinterpret_cast<const bf16x8*>(Bs + (wc * 64 + j * 16 + l15) * BK + lhi * 8);
        #pragma unroll
        for (int i = 0; i < 4; ++i)
            #pragma unroll
            for (int j = 0; j < 4; ++j)
                acc[i][j] = __builtin_amdgcn_mfma_f32_16x16x32_bf16(af[i], bfr[j], acc[i][j], 0, 0, 0);
    }

    const bool isV = (tn >= 2048);
    #pragma unroll
    for (int i = 0; i < 4; ++i) {
        #pragma unroll
        for (int j = 0; j < 4; ++j) {
            int col = tn + wc * 64 + j * 16 + l15;
            int row0 = tm + wr * 64 + i * 16 + lhi * 4;
            if (!isV) {
                #pragma unroll
                for (int r = 0; r < 4; ++r)
                    Cqk[(size_t)(row0 + r) * 2048 + col] = f2bf(acc[i][j][r]);
            } else {
                unsigned short t[4];
                #pragma unroll
                for (int r = 0; r < 4; ++r) t[r] = f2bf(acc[i][j][r]);
                *reinterpret_cast<uint2*>(Vt + (size_t)(col - 2048) * M_ + row0) =
                    *reinterpret_cast<const uint2*>(t);
            }
        }
    }
}

// ---- flash attention (causal), split-K, single-buffered 32KB LDS ------------
// QK: [4096][2048] bf16 — Q cols 0..1023 (pre-scaled), K cols 1024..2047
// VT: [1024][4096] bf16 — row h*64+d, col b*2048+k
// grid 2048 x 256: block owns 32 q rows; wave w handles tiles kt=w, w+4, ...
// (static softmax => partials combine linearly). Per-wave SINGLE-buffered
// 8KB K/V stage -> 32KB/block -> 5 blocks/CU (20 waves/CU, ~3x round 8).
// Within-tile latency split: issue K then V loads; vmcnt(4) before QK (V in
// flight under QK+softmax); vmcnt(0) only before PV. Exposed K latency is
// covered by TLP. Epilogue: two-phase partial combine reusing the 4KB buffers.

__global__ __launch_bounds__(256, 5) void attn_kernel(
    const unsigned short* __restrict__ QK,
    const unsigned short* __restrict__ VT,
    unsigned short* __restrict__ Ctx)
{
    __shared__ unsigned short Ks[4][32 * 64];  // per-wave [kv][d], swz ^(row&7)
    __shared__ unsigned short Vs[4][64 * 32];  // per-wave [d][kv], swz ^((d>>1)&3)

    const int tid  = threadIdx.x;
    const int lane = tid & 63;
    const int wid  = tid >> 6;          // 0..3
    const int l31  = lane & 31;
    const int hi   = lane >> 5;

    // XCD-aware remap (lin%8 = XCD); heavy q-blocks first
    const int lin  = blockIdx.x;
    const int idx  = lin >> 3;          // 0..255
    const int bh   = (lin & 7) + 8 * (idx & 3);
    const int qb   = 63 - (idx >> 2);   // 0..63, heavy first
    const int b = bh >> 4, h = bh & 15;
    const size_t baseRow = (size_t)b * S_;
    const int qw = qb * 32;
    const int q  = qw + l31;

    // Q B-fragments (same 32 q rows for all 4 waves; pre-scaled at cast)
    bf16x8 qf[4];
    #pragma unroll
    for (int s = 0; s < 4; ++s)
        qf[s] = *reinterpret_cast<const bf16x8*>(
            QK + (baseRow + q) * 2048 + h * HD_ + s * 16 + hi * 8);

    float l = 0.0f;
    f32x16 oacc[2] = {};

    const int nkt = qb + 1;             // KV tiles of 32

    // staging indices (per-wave lane)
    const int kr  = lane >> 3;          // K: row-in-8-group
    const int ks  = lane & 7;           // K: 16B slot (8 per 128B row)
    const int vr  = lane >> 2;          // V: row-in-16-group
    const int vsl = lane & 3;           // V: 16B slot (4 per 64B row)

#define STAGE_K(kt_) do {                                                      \
    int k0_ = (kt_) * 32;                                                      \
    _Pragma("unroll")                                                          \
    for (int i_ = 0; i_ < 4; ++i_) {                                           \
        int krow_ = i_ * 8 + kr;                                               \
        int ksc_  = (ks ^ kr) * 8;                                             \
        gload_lds16(QK + (baseRow + k0_ + krow_) * 2048 + D_ + h * HD_ + ksc_, \
                    (void*)(&Ks[wid][i_ * 512]));                              \
    } } while (0)
#define STAGE_V(kt_) do {                                                      \
    int k0_ = (kt_) * 32;                                                      \
    _Pragma("unroll")                                                          \
    for (int i_ = 0; i_ < 4; ++i_) {                                           \
        int vrow_ = i_ * 16 + vr;                                              \
        int vsc_  = (vsl ^ ((vrow_ >> 1) & 3)) * 8;                            \
        gload_lds16(VT + (size_t)(h * HD_ + vrow_) * M_ + baseRow + k0_ + vsc_,\
                    (void*)(&Vs[wid][i_ * 512]));                              \
    } } while (0)

    if (wid < nkt) {
        for (int kt = wid; kt < nkt; kt += 4) {
            STAGE_K(kt);                // 4 loads
            STAGE_V(kt);                // 4 loads
            asm volatile("s_waitcnt vmcnt(4)" ::: "memory");   // K staged; V in flight
            __builtin_amdgcn_sched_barrier(0);

            const unsigned short* Kc = &Ks[wid][0];

            // swapped QK^T: sc[row=kv local][col=q=l31]
            f32x16 sc = {};
            #pragma unroll
            for (int s = 0; s < 4; ++s) {
                int sl = (2 * s + hi) ^ (l31 & 7);
                bf16x8 kf = *reinterpret_cast<const bf16x8*>(Kc + l31 * 64 + sl * 8);
                sc = __builtin_amdgcn_mfma_f32_32x32x16_bf16(kf, qf[s], sc, 0, 0, 0);
            }

            if (kt == qb) {   // diagonal tile: causal mask
                #pragma unroll
                for (int r = 0; r < 16; ++r) {
                    int kl = kt * 32 + (r & 3) + 8 * (r >> 2) + 4 * hi;
                    if (kl > q) sc[r] = -INFINITY;
                }
            }

            // static softmax (exp2 domain) -> packed bf16 P
            unsigned int g0, g1, g2, g3, g4, g5, g6, g7;
            float ps = 0.0f;
            {
                float e0, e1, e2, e3;
                e0=exp2f(sc[0]);  e1=exp2f(sc[1]);  e2=exp2f(sc[2]);  e3=exp2f(sc[3]);
                ps += (e0+e1)+(e2+e3); g0 = cvt_pk_bf16(e0,e1); g1 = cvt_pk_bf16(e2,e3);
                e0=exp2f(sc[4]);  e1=exp2f(sc[5]);  e2=exp2f(sc[6]);  e3=exp2f(sc[7]);
                ps += (e0+e1)+(e2+e3); g2 = cvt_pk_bf16(e0,e1); g3 = cvt_pk_bf16(e2,e3);
                e0=exp2f(sc[8]);  e1=exp2f(sc[9]);  e2=exp2f(sc[10]); e3=exp2f(sc[11]);
                ps += (e0+e1)+(e2+e3); g4 = cvt_pk_bf16(e0,e1); g5 = cvt_pk_bf16(e2,e3);
                e0=exp2f(sc[12]); e1=exp2f(sc[13]); e2=exp2f(sc[14]); e3=exp2f(sc[15]);
                ps += (e0+e1)+(e2+e3); g6 = cvt_pk_bf16(e0,e1); g7 = cvt_pk_bf16(e2,e3);
            }
            l += ps;

            // P -> A-fragments via permlane32_swap
            asm("v_permlane32_swap_b32 %0, %1" : "+v"(g0), "+v"(g2));
            asm("v_permlane32_swap_b32 %0, %1" : "+v"(g1), "+v"(g3));
            asm("v_permlane32_swap_b32 %0, %1" : "+v"(g4), "+v"(g6));
            asm("v_permlane32_swap_b32 %0, %1" : "+v"(g5), "+v"(g7));
            bf16x8 pa0 = __builtin_bit_cast(bf16x8, (u32x4){g0, g1, g2, g3});
            bf16x8 pa1 = __builtin_bit_cast(bf16x8, (u32x4){g4, g5, g6, g7});

            asm volatile("s_waitcnt vmcnt(0)" ::: "memory");   // V staged
            __builtin_amdgcn_sched_barrier(0);

            const unsigned short* Vc = &Vs[wid][0];
            bf16x8 vf[2][2];
            #pragma unroll
            for (int dt = 0; dt < 2; ++dt)
                #pragma unroll
                for (int s = 0; s < 2; ++s) {
                    int d = dt * 32 + l31;
                    int sl = (2 * s + hi) ^ ((d >> 1) & 3);
                    vf[dt][s] = *reinterpret_cast<const bf16x8*>(Vc + d * 32 + sl * 8);
                }

            // O += P · V   (pure MFMA cluster)
            __builtin_amdgcn_s_setprio(1);
            #pragma unroll
            for (int dt = 0; dt < 2; ++dt) {
                oacc[dt] = __builtin_amdgcn_mfma_f32_32x32x16_bf16(pa0, vf[dt][0], oacc[dt], 0, 0, 0);
                oacc[dt] = __builtin_amdgcn_mfma_f32_32x32x16_bf16(pa1, vf[dt][1], oacc[dt], 0, 0, 0);
            }
            __builtin_amdgcn_s_setprio(0);
        }
    }
#undef STAGE_K
#undef STAGE_V

    // ---- split-K combine: two phases reusing the 4KB per-wave buffers ----
    float* Olw = (float*)&Ks[wid][0];          // 32q x 32d f32 = 4KB
    float* Lpw = (float*)&Vs[wid][0];          // 32 f32
    float lc = l + __shfl_xor(l, 32, 64);
    if (hi == 0) Lpw[l31] = lc;

    const int cq = tid >> 3;
    const int cd = (tid & 7) * 4;
    float inv = 0.0f;
    #pragma unroll
    for (int ph = 0; ph < 2; ++ph) {
        __syncthreads();                       // prior reads of Ks/Vs complete
        #pragma unroll
        for (int r = 0; r < 16; ++r) {
            int qr = (r & 3) + 8 * (r >> 2) + 4 * hi;
            Olw[qr * 32 + l31] = oacc[ph][r];
        }
        __syncthreads();
        float s0 = 0, s1 = 0, s2 = 0, s3 = 0, lt = 0;
        #pragma unroll
        for (int w = 0; w < 4; ++w) {
            const float* O = (const float*)&Ks[w][0];
            f32x4 a = *reinterpret_cast<const f32x4*>(O + cq * 32 + cd);
            s0 += a[0]; s1 += a[1]; s2 += a[2]; s3 += a[3];
            if (ph == 0) lt += ((const float*)&Vs[w][0])[cq];
        }
        if (ph == 0) inv = 1.0f / lt;
        unsigned short o[4];
        o[0] = f2bf(s0 * inv); o[1] = f2bf(s1 * inv);
        o[2] = f2bf(s2 * inv); o[3] = f2bf(s3 * inv);
        *reinterpret_cast<uint2*>(
            Ctx + (baseRow + qw + cq) * D_ + h * HD_ + ph * 32 + cd) =
            *reinterpret_cast<const uint2*>(o);
    }
}

// ---- launch -----------------------------------------------------------------

extern "C" void kernel_launch(void* const* d_in, const int* in_sizes, int n_in,
                              void* d_out, int out_size, void* d_ws, size_t ws_size,
                              hipStream_t stream) {
    const float* x  = (const float*)d_in[0];
    const float* wq = (const float*)d_in[1];
    const float* wk = (const float*)d_in[2];
    const float* wv = (const float*)d_in[3];
    const float* wo = (const float*)d_in[4];
    const float* bo = (const float*)d_in[5];

    unsigned short* ws = (unsigned short*)d_ws;
    unsigned short* xb  = ws;                       // [4096][1024]  8 MB
    unsigned short* wqb = xb  + 4194304;            // wq|wk|wv stacked
    unsigned short* wob = wqb + 3145728;
    unsigned short* QKb = wob + 1048576;            // [4096][2048] 16 MB
    unsigned short* VT  = QKb + 8388608;            // [1024][4096]  8 MB
    unsigned short* Cx  = VT  + 4194304;            // [4096][1024]  8 MB

    cast_all<<<4096, 256, 0, stream>>>(x, wq, wk, wv, wo, xb);

    // merged QKV projection (V written transposed)
    gemm_qkv<<<dim3(24, 32), 256, 0, stream>>>(xb, wqb, QKb, VT);

    // causal flash attention, split-K over 4 waves, 32KB LDS
    attn_kernel<<<2048, 256, 0, stream>>>(QKb, VT, Cx);

    // out = ctx @ Wo^T + b_out  (fp32 out)
    gemm_bt<true, float><<<dim3(8, 32), 256, 0, stream>>>(
        Cx, wob, (float*)d_out, bo, M_, D_, D_);
}

// Round 11
// 110.596 us; speedup vs baseline: 1.2788x; 1.2628x over previous
//
#include <hip/hip_runtime.h>
#include <stdint.h>

// Problem constants
#define B_  2
#define S_  2048
#define D_  1024
#define H_  16
#define HD_ 64
#define M_  (B_*S_)   // 4096 rows

typedef __attribute__((ext_vector_type(8)))  short bf16x8;   // 8 bf16 in 4 VGPRs
typedef __attribute__((ext_vector_type(4)))  float f32x4;
typedef __attribute__((ext_vector_type(16))) float f32x16;
typedef __attribute__((ext_vector_type(4)))  unsigned int u32x4;

// ---- helpers ----------------------------------------------------------------

__device__ __forceinline__ unsigned short f2bf(float f) {
    unsigned int u = __float_as_uint(f);
    unsigned int r = (u + 0x7fffu + ((u >> 16) & 1u)) >> 16;
    return (unsigned short)r;
}

__device__ __forceinline__ unsigned int cvt_pk_bf16(float lo, float hi) {
    unsigned int r;
    asm("v_cvt_pk_bf16_f32 %0, %1, %2" : "=v"(r) : "v"(lo), "v"(hi));
    return r;
}

__device__ __forceinline__ void gload_lds16(const void* g, void* l) {
    __builtin_amdgcn_global_load_lds(
        (const __attribute__((address_space(1))) unsigned int*)g,
        (__attribute__((address_space(3))) unsigned int*)l,
        16, 0, 0);
}

// ---- fused fp32 -> bf16 cast; Wq/Wk pre-scaled by sqrt(log2(e)/8) -----------

__global__ __launch_bounds__(256) void cast_all(
    const float* __restrict__ x,
    const float* __restrict__ wq, const float* __restrict__ wk,
    const float* __restrict__ wv, const float* __restrict__ wo,
    unsigned short* __restrict__ dst)
{
    int b = blockIdx.x;
    const float* src;
    size_t soff, doff;
    float sc = 1.0f;
    if (b < 2048) {
        src = x; soff = (size_t)b * 2048; doff = soff;
    } else {
        int r  = (b - 2048) >> 9;
        int lb = (b - 2048) & 511;
        src = (r == 0) ? wq : (r == 1) ? wk : (r == 2) ? wv : wo;
        if (r <= 1) sc = 0.4246609093670877f;   // sqrt(log2(e)/sqrt(64))
        soff = (size_t)lb * 2048;
        doff = (size_t)4194304 + (size_t)r * 1048576 + soff;
    }
    int idx = threadIdx.x * 8;
    float4 a = *reinterpret_cast<const float4*>(src + soff + idx);
    float4 c = *reinterpret_cast<const float4*>(src + soff + idx + 4);
    unsigned short t[8];
    t[0]=f2bf(a.x*sc); t[1]=f2bf(a.y*sc); t[2]=f2bf(a.z*sc); t[3]=f2bf(a.w*sc);
    t[4]=f2bf(c.x*sc); t[5]=f2bf(c.y*sc); t[6]=f2bf(c.z*sc); t[7]=f2bf(c.w*sc);
    *reinterpret_cast<uint4*>(dst + doff + idx) = *reinterpret_cast<const uint4*>(t);
}

// ---- bf16 GEMM, C[M,N] = A[M,K] * Bm[N,K]^T (+bias) -------------------------

template <bool BIAS, typename CT>
__global__ __launch_bounds__(256) void gemm_bt(
    const unsigned short* __restrict__ A,
    const unsigned short* __restrict__ Bm,
    CT* __restrict__ C,
    const float* __restrict__ bias,
    int M, int N, int K)
{
    constexpr int BK = 32;
    __shared__ unsigned short As[128 * BK];
    __shared__ unsigned short Bs[128 * BK];

    const int tid  = threadIdx.x;
    const int lane = tid & 63;
    const int wid  = tid >> 6;
    const int wr = wid >> 1, wc = wid & 1;
    const int l15 = lane & 15, lhi = lane >> 4;
    const int tm = blockIdx.y * 128, tn = blockIdx.x * 128;

    f32x4 acc[4][4] = {};

    const int srow = (lane >> 2);
    const int scol = (lane & 3) * 8;

    for (int k0 = 0; k0 < K; k0 += BK) {
        __syncthreads();
        #pragma unroll
        for (int i = 0; i < 2; ++i) {
            int chunk = wid * 2 + i;
            int row = chunk * 16 + srow;
            gload_lds16(A  + (size_t)(tm + row) * K + k0 + scol, (void*)(As + chunk * 512));
            gload_lds16(Bm + (size_t)(tn + row) * K + k0 + scol, (void*)(Bs + chunk * 512));
        }
        __syncthreads();

        bf16x8 af[4], bfr[4];
        #pragma unroll
        for (int i = 0; i < 4; ++i)
            af[i] = *reinterpret_cast<const bf16x8*>(As + (wr * 64 + i * 16 + l15) * BK + lhi * 8);
        #pragma unroll
        for (int j = 0; j < 4; ++j)
            bfr[j] = *reinterpret_cast<const bf16x8*>(Bs + (wc * 64 + j * 16 + l15) * BK + lhi * 8);
        #pragma unroll
        for (int i = 0; i < 4; ++i)
            #pragma unroll
            for (int j = 0; j < 4; ++j)
                acc[i][j] = __builtin_amdgcn_mfma_f32_16x16x32_bf16(af[i], bfr[j], acc[i][j], 0, 0, 0);
    }

    #pragma unroll
    for (int i = 0; i < 4; ++i) {
        #pragma unroll
        for (int j = 0; j < 4; ++j) {
            int col = tn + wc * 64 + j * 16 + l15;
            float bv = BIAS ? bias[col] : 0.0f;
            #pragma unroll
            for (int r = 0; r < 4; ++r) {
                int row = tm + wr * 64 + i * 16 + lhi * 4 + r;
                float v = acc[i][j][r] + bv;
                if constexpr (sizeof(CT) == 2) {
                    ((unsigned short*)C)[(size_t)row * N + col] = f2bf(v);
                } else {
                    ((float*)C)[(size_t)row * N + col] = v;
                }
            }
        }
    }
}

// ---- merged QKV projection: [4096][3072] = x @ [Wq;Wk;Wv]^T -----------------

__global__ __launch_bounds__(256) void gemm_qkv(
    const unsigned short* __restrict__ A,
    const unsigned short* __restrict__ Bm,
    unsigned short* __restrict__ Cqk,
    unsigned short* __restrict__ Vt)
{
    constexpr int BK = 32, K = 1024;
    __shared__ unsigned short As[128 * BK];
    __shared__ unsigned short Bs[128 * BK];

    const int tid  = threadIdx.x;
    const int lane = tid & 63;
    const int wid  = tid >> 6;
    const int wr = wid >> 1, wc = wid & 1;
    const int l15 = lane & 15, lhi = lane >> 4;
    const int tm = blockIdx.y * 128, tn = blockIdx.x * 128;

    f32x4 acc[4][4] = {};

    const int srow = (lane >> 2);
    const int scol = (lane & 3) * 8;

    for (int k0 = 0; k0 < K; k0 += BK) {
        __syncthreads();
        #pragma unroll
        for (int i = 0; i < 2; ++i) {
            int chunk = wid * 2 + i;
            int row = chunk * 16 + srow;
            gload_lds16(A  + (size_t)(tm + row) * K + k0 + scol, (void*)(As + chunk * 512));
            gload_lds16(Bm + (size_t)(tn + row) * K + k0 + scol, (void*)(Bs + chunk * 512));
        }
        __syncthreads();

        bf16x8 af[4], bfr[4];
        #pragma unroll
        for (int i = 0; i < 4; ++i)
            af[i] = *reinterpret_cast<const bf16x8*>(As + (wr * 64 + i * 16 + l15) * BK + lhi * 8);
        #pragma unroll
        for (int j = 0; j < 4; ++j)
            bfr[j] = *reinterpret_cast<const bf16x8*>(Bs + (wc * 64 + j * 16 + l15) * BK + lhi * 8);
        #pragma unroll
        for (int i = 0; i < 4; ++i)
            #pragma unroll
            for (int j = 0; j < 4; ++j)
                acc[i][j] = __builtin_amdgcn_mfma_f32_16x16x32_bf16(af[i], bfr[j], acc[i][j], 0, 0, 0);
    }

    const bool isV = (tn >= 2048);
    #pragma unroll
    for (int i = 0; i < 4; ++i) {
        #pragma unroll
        for (int j = 0; j < 4; ++j) {
            int col = tn + wc * 64 + j * 16 + l15;
            int row0 = tm + wr * 64 + i * 16 + lhi * 4;
            if (!isV) {
                #pragma unroll
                for (int r = 0; r < 4; ++r)
                    Cqk[(size_t)(row0 + r) * 2048 + col] = f2bf(acc[i][j][r]);
            } else {
                unsigned short t[4];
                #pragma unroll
                for (int r = 0; r < 4; ++r) t[r] = f2bf(acc[i][j][r]);
                *reinterpret_cast<uint2*>(Vt + (size_t)(col - 2048) * M_ + row0) =
                    *reinterpret_cast<const uint2*>(t);
            }
        }
    }
}

// ---- flash attention (causal), split-K, single-buffered 32KB LDS ------------
// QK: [4096][2048] bf16 — Q cols 0..1023 (pre-scaled), K cols 1024..2047
// VT: [1024][4096] bf16 — row h*64+d, col b*2048+k
// grid 2048 x 256: block owns 32 q rows; wave w handles tiles kt=w, w+4, ...
// (static softmax => partials combine linearly). Per-wave SINGLE-buffered
// 8KB K/V stage -> 32KB/block. launch_bounds(256,4): VGPR cap 128 (kernel
// needs ~88, NO spills — round 10's (256,5) forced 48 VGPR and 40MB of
// scratch traffic). At 88 VGPR HW grants 4 waves/SIMD -> 4 blocks/CU (~50%).
// Within-tile latency split: vmcnt(4) before QK (V in flight under
// QK+softmax); vmcnt(0) only before PV. Exposed K latency covered by TLP.

__global__ __launch_bounds__(256, 4) void attn_kernel(
    const unsigned short* __restrict__ QK,
    const unsigned short* __restrict__ VT,
    unsigned short* __restrict__ Ctx)
{
    __shared__ unsigned short Ks[4][32 * 64];  // per-wave [kv][d], swz ^(row&7)
    __shared__ unsigned short Vs[4][64 * 32];  // per-wave [d][kv], swz ^((d>>1)&3)

    const int tid  = threadIdx.x;
    const int lane = tid & 63;
    const int wid  = tid >> 6;          // 0..3
    const int l31  = lane & 31;
    const int hi   = lane >> 5;

    // XCD-aware remap (lin%8 = XCD); heavy q-blocks first
    const int lin  = blockIdx.x;
    const int idx  = lin >> 3;          // 0..255
    const int bh   = (lin & 7) + 8 * (idx & 3);
    const int qb   = 63 - (idx >> 2);   // 0..63, heavy first
    const int b = bh >> 4, h = bh & 15;
    const size_t baseRow = (size_t)b * S_;
    const int qw = qb * 32;
    const int q  = qw + l31;

    // Q B-fragments (same 32 q rows for all 4 waves; pre-scaled at cast)
    bf16x8 qf[4];
    #pragma unroll
    for (int s = 0; s < 4; ++s)
        qf[s] = *reinterpret_cast<const bf16x8*>(
            QK + (baseRow + q) * 2048 + h * HD_ + s * 16 + hi * 8);

    float l = 0.0f;
    f32x16 oacc[2] = {};

    const int nkt = qb + 1;             // KV tiles of 32

    // staging indices (per-wave lane)
    const int kr  = lane >> 3;          // K: row-in-8-group
    const int ks  = lane & 7;           // K: 16B slot (8 per 128B row)
    const int vr  = lane >> 2;          // V: row-in-16-group
    const int vsl = lane & 3;           // V: 16B slot (4 per 64B row)

#define STAGE_K(kt_) do {                                                      \
    int k0_ = (kt_) * 32;                                                      \
    _Pragma("unroll")                                                          \
    for (int i_ = 0; i_ < 4; ++i_) {                                           \
        int krow_ = i_ * 8 + kr;                                               \
        int ksc_  = (ks ^ kr) * 8;                                             \
        gload_lds16(QK + (baseRow + k0_ + krow_) * 2048 + D_ + h * HD_ + ksc_, \
                    (void*)(&Ks[wid][i_ * 512]));                              \
    } } while (0)
#define STAGE_V(kt_) do {                                                      \
    int k0_ = (kt_) * 32;                                                      \
    _Pragma("unroll")                                                          \
    for (int i_ = 0; i_ < 4; ++i_) {                                           \
        int vrow_ = i_ * 16 + vr;                                              \
        int vsc_  = (vsl ^ ((vrow_ >> 1) & 3)) * 8;                            \
        gload_lds16(VT + (size_t)(h * HD_ + vrow_) * M_ + baseRow + k0_ + vsc_,\
                    (void*)(&Vs[wid][i_ * 512]));                              \
    } } while (0)

    if (wid < nkt) {
        for (int kt = wid; kt < nkt; kt += 4) {
            STAGE_K(kt);                // 4 loads
            STAGE_V(kt);                // 4 loads
            asm volatile("s_waitcnt vmcnt(4)" ::: "memory");   // K staged; V in flight
            __builtin_amdgcn_sched_barrier(0);

            const unsigned short* Kc = &Ks[wid][0];

            // swapped QK^T: sc[row=kv local][col=q=l31]
            f32x16 sc = {};
            #pragma unroll
            for (int s = 0; s < 4; ++s) {
                int sl = (2 * s + hi) ^ (l31 & 7);
                bf16x8 kf = *reinterpret_cast<const bf16x8*>(Kc + l31 * 64 + sl * 8);
                sc = __builtin_amdgcn_mfma_f32_32x32x16_bf16(kf, qf[s], sc, 0, 0, 0);
            }

            if (kt == qb) {   // diagonal tile: causal mask
                #pragma unroll
                for (int r = 0; r < 16; ++r) {
                    int kl = kt * 32 + (r & 3) + 8 * (r >> 2) + 4 * hi;
                    if (kl > q) sc[r] = -INFINITY;
                }
            }

            // static softmax (exp2 domain) -> packed bf16 P
            unsigned int g0, g1, g2, g3, g4, g5, g6, g7;
            float ps = 0.0f;
            {
                float e0, e1, e2, e3;
                e0=exp2f(sc[0]);  e1=exp2f(sc[1]);  e2=exp2f(sc[2]);  e3=exp2f(sc[3]);
                ps += (e0+e1)+(e2+e3); g0 = cvt_pk_bf16(e0,e1); g1 = cvt_pk_bf16(e2,e3);
                e0=exp2f(sc[4]);  e1=exp2f(sc[5]);  e2=exp2f(sc[6]);  e3=exp2f(sc[7]);
                ps += (e0+e1)+(e2+e3); g2 = cvt_pk_bf16(e0,e1); g3 = cvt_pk_bf16(e2,e3);
                e0=exp2f(sc[8]);  e1=exp2f(sc[9]);  e2=exp2f(sc[10]); e3=exp2f(sc[11]);
                ps += (e0+e1)+(e2+e3); g4 = cvt_pk_bf16(e0,e1); g5 = cvt_pk_bf16(e2,e3);
                e0=exp2f(sc[12]); e1=exp2f(sc[13]); e2=exp2f(sc[14]); e3=exp2f(sc[15]);
                ps += (e0+e1)+(e2+e3); g6 = cvt_pk_bf16(e0,e1); g7 = cvt_pk_bf16(e2,e3);
            }
            l += ps;

            // P -> A-fragments via permlane32_swap
            asm("v_permlane32_swap_b32 %0, %1" : "+v"(g0), "+v"(g2));
            asm("v_permlane32_swap_b32 %0, %1" : "+v"(g1), "+v"(g3));
            asm("v_permlane32_swap_b32 %0, %1" : "+v"(g4), "+v"(g6));
            asm("v_permlane32_swap_b32 %0, %1" : "+v"(g5), "+v"(g7));
            bf16x8 pa0 = __builtin_bit_cast(bf16x8, (u32x4){g0, g1, g2, g3});
            bf16x8 pa1 = __builtin_bit_cast(bf16x8, (u32x4){g4, g5, g6, g7});

            asm volatile("s_waitcnt vmcnt(0)" ::: "memory");   // V staged
            __builtin_amdgcn_sched_barrier(0);

            const unsigned short* Vc = &Vs[wid][0];
            bf16x8 vf[2][2];
            #pragma unroll
            for (int dt = 0; dt < 2; ++dt)
                #pragma unroll
                for (int s = 0; s < 2; ++s) {
                    int d = dt * 32 + l31;
                    int sl = (2 * s + hi) ^ ((d >> 1) & 3);
                    vf[dt][s] = *reinterpret_cast<const bf16x8*>(Vc + d * 32 + sl * 8);
                }

            // O += P · V   (pure MFMA cluster)
            __builtin_amdgcn_s_setprio(1);
            #pragma unroll
            for (int dt = 0; dt < 2; ++dt) {
                oacc[dt] = __builtin_amdgcn_mfma_f32_32x32x16_bf16(pa0, vf[dt][0], oacc[dt], 0, 0, 0);
                oacc[dt] = __builtin_amdgcn_mfma_f32_32x32x16_bf16(pa1, vf[dt][1], oacc[dt], 0, 0, 0);
            }
            __builtin_amdgcn_s_setprio(0);
        }
    }
#undef STAGE_K
#undef STAGE_V

    // ---- split-K combine: two phases reusing the 4KB per-wave buffers ----
    float* Olw = (float*)&Ks[wid][0];          // 32q x 32d f32 = 4KB
    float* Lpw = (float*)&Vs[wid][0];          // 32 f32
    float lc = l + __shfl_xor(l, 32, 64);
    if (hi == 0) Lpw[l31] = lc;

    const int cq = tid >> 3;
    const int cd = (tid & 7) * 4;
    float inv = 0.0f;
    #pragma unroll
    for (int ph = 0; ph < 2; ++ph) {
        __syncthreads();                       // prior reads of Ks/Vs complete
        #pragma unroll
        for (int r = 0; r < 16; ++r) {
            int qr = (r & 3) + 8 * (r >> 2) + 4 * hi;
            Olw[qr * 32 + l31] = oacc[ph][r];
        }
        __syncthreads();
        float s0 = 0, s1 = 0, s2 = 0, s3 = 0, lt = 0;
        #pragma unroll
        for (int w = 0; w < 4; ++w) {
            const float* O = (const float*)&Ks[w][0];
            f32x4 a = *reinterpret_cast<const f32x4*>(O + cq * 32 + cd);
            s0 += a[0]; s1 += a[1]; s2 += a[2]; s3 += a[3];
            if (ph == 0) lt += ((const float*)&Vs[w][0])[cq];
        }
        if (ph == 0) inv = 1.0f / lt;
        unsigned short o[4];
        o[0] = f2bf(s0 * inv); o[1] = f2bf(s1 * inv);
        o[2] = f2bf(s2 * inv); o[3] = f2bf(s3 * inv);
        *reinterpret_cast<uint2*>(
            Ctx + (baseRow + qw + cq) * D_ + h * HD_ + ph * 32 + cd) =
            *reinterpret_cast<const uint2*>(o);
    }
}

// ---- launch -----------------------------------------------------------------

extern "C" void kernel_launch(void* const* d_in, const int* in_sizes, int n_in,
                              void* d_out, int out_size, void* d_ws, size_t ws_size,
                              hipStream_t stream) {
    const float* x  = (const float*)d_in[0];
    const float* wq = (const float*)d_in[1];
    const float* wk = (const float*)d_in[2];
    const float* wv = (const float*)d_in[3];
    const float* wo = (const float*)d_in[4];
    const float* bo = (const float*)d_in[5];

    unsigned short* ws = (unsigned short*)d_ws;
    unsigned short* xb  = ws;                       // [4096][1024]  8 MB
    unsigned short* wqb = xb  + 4194304;            // wq|wk|wv stacked
    unsigned short* wob = wqb + 3145728;
    unsigned short* QKb = wob + 1048576;            // [4096][2048] 16 MB
    unsigned short* VT  = QKb + 8388608;            // [1024][4096]  8 MB
    unsigned short* Cx  = VT  + 4194304;            // [4096][1024]  8 MB

    cast_all<<<4096, 256, 0, stream>>>(x, wq, wk, wv, wo, xb);

    // merged QKV projection (V written transposed)
    gemm_qkv<<<dim3(24, 32), 256, 0, stream>>>(xb, wqb, QKb, VT);

    // causal flash attention, split-K over 4 waves, 32KB LDS
    attn_kernel<<<2048, 256, 0, stream>>>(QKb, VT, Cx);

    // out = ctx @ Wo^T + b_out  (fp32 out)
    gemm_bt<true, float><<<dim3(8, 32), 256, 0, stream>>>(
        Cx, wob, (float*)d_out, bo, M_, D_, D_);
}

// Round 12
// 109.054 us; speedup vs baseline: 1.2968x; 1.0141x over previous
//
#include <hip/hip_runtime.h>
#include <stdint.h>

// Problem constants
#define B_  2
#define S_  2048
#define D_  1024
#define H_  16
#define HD_ 64
#define M_  (B_*S_)   // 4096 rows

typedef __attribute__((ext_vector_type(8)))  short bf16x8;   // 8 bf16 in 4 VGPRs
typedef __attribute__((ext_vector_type(4)))  float f32x4;
typedef __attribute__((ext_vector_type(16))) float f32x16;
typedef __attribute__((ext_vector_type(4)))  unsigned int u32x4;

// ---- helpers ----------------------------------------------------------------

__device__ __forceinline__ unsigned short f2bf(float f) {
    unsigned int u = __float_as_uint(f);
    unsigned int r = (u + 0x7fffu + ((u >> 16) & 1u)) >> 16;
    return (unsigned short)r;
}

__device__ __forceinline__ unsigned int cvt_pk_bf16(float lo, float hi) {
    unsigned int r;
    asm("v_cvt_pk_bf16_f32 %0, %1, %2" : "=v"(r) : "v"(lo), "v"(hi));
    return r;
}

__device__ __forceinline__ void gload_lds16(const void* g, void* l) {
    __builtin_amdgcn_global_load_lds(
        (const __attribute__((address_space(1))) unsigned int*)g,
        (__attribute__((address_space(3))) unsigned int*)l,
        16, 0, 0);
}

// ---- fused fp32 -> bf16 cast; Wq/Wk pre-scaled by sqrt(log2(e)/8) -----------

__global__ __launch_bounds__(256) void cast_all(
    const float* __restrict__ x,
    const float* __restrict__ wq, const float* __restrict__ wk,
    const float* __restrict__ wv, const float* __restrict__ wo,
    unsigned short* __restrict__ dst)
{
    int b = blockIdx.x;
    const float* src;
    size_t soff, doff;
    float sc = 1.0f;
    if (b < 2048) {
        src = x; soff = (size_t)b * 2048; doff = soff;
    } else {
        int r  = (b - 2048) >> 9;
        int lb = (b - 2048) & 511;
        src = (r == 0) ? wq : (r == 1) ? wk : (r == 2) ? wv : wo;
        if (r <= 1) sc = 0.4246609093670877f;   // sqrt(log2(e)/sqrt(64))
        soff = (size_t)lb * 2048;
        doff = (size_t)4194304 + (size_t)r * 1048576 + soff;
    }
    int idx = threadIdx.x * 8;
    float4 a = *reinterpret_cast<const float4*>(src + soff + idx);
    float4 c = *reinterpret_cast<const float4*>(src + soff + idx + 4);
    unsigned short t[8];
    t[0]=f2bf(a.x*sc); t[1]=f2bf(a.y*sc); t[2]=f2bf(a.z*sc); t[3]=f2bf(a.w*sc);
    t[4]=f2bf(c.x*sc); t[5]=f2bf(c.y*sc); t[6]=f2bf(c.z*sc); t[7]=f2bf(c.w*sc);
    *reinterpret_cast<uint4*>(dst + doff + idx) = *reinterpret_cast<const uint4*>(t);
}

// ---- bf16 GEMM, C[M,N] = A[M,K] * Bm[N,K]^T (+bias) -------------------------

template <bool BIAS, typename CT>
__global__ __launch_bounds__(256) void gemm_bt(
    const unsigned short* __restrict__ A,
    const unsigned short* __restrict__ Bm,
    CT* __restrict__ C,
    const float* __restrict__ bias,
    int M, int N, int K)
{
    constexpr int BK = 32;
    __shared__ unsigned short As[128 * BK];
    __shared__ unsigned short Bs[128 * BK];

    const int tid  = threadIdx.x;
    const int lane = tid & 63;
    const int wid  = tid >> 6;
    const int wr = wid >> 1, wc = wid & 1;
    const int l15 = lane & 15, lhi = lane >> 4;
    const int tm = blockIdx.y * 128, tn = blockIdx.x * 128;

    f32x4 acc[4][4] = {};

    const int srow = (lane >> 2);
    const int scol = (lane & 3) * 8;

    for (int k0 = 0; k0 < K; k0 += BK) {
        __syncthreads();
        #pragma unroll
        for (int i = 0; i < 2; ++i) {
            int chunk = wid * 2 + i;
            int row = chunk * 16 + srow;
            gload_lds16(A  + (size_t)(tm + row) * K + k0 + scol, (void*)(As + chunk * 512));
            gload_lds16(Bm + (size_t)(tn + row) * K + k0 + scol, (void*)(Bs + chunk * 512));
        }
        __syncthreads();

        bf16x8 af[4], bfr[4];
        #pragma unroll
        for (int i = 0; i < 4; ++i)
            af[i] = *reinterpret_cast<const bf16x8*>(As + (wr * 64 + i * 16 + l15) * BK + lhi * 8);
        #pragma unroll
        for (int j = 0; j < 4; ++j)
            bfr[j] = *reinterpret_cast<const bf16x8*>(Bs + (wc * 64 + j * 16 + l15) * BK + lhi * 8);
        #pragma unroll
        for (int i = 0; i < 4; ++i)
            #pragma unroll
            for (int j = 0; j < 4; ++j)
                acc[i][j] = __builtin_amdgcn_mfma_f32_16x16x32_bf16(af[i], bfr[j], acc[i][j], 0, 0, 0);
    }

    #pragma unroll
    for (int i = 0; i < 4; ++i) {
        #pragma unroll
        for (int j = 0; j < 4; ++j) {
            int col = tn + wc * 64 + j * 16 + l15;
            float bv = BIAS ? bias[col] : 0.0f;
            #pragma unroll
            for (int r = 0; r < 4; ++r) {
                int row = tm + wr * 64 + i * 16 + lhi * 4 + r;
                float v = acc[i][j][r] + bv;
                if constexpr (sizeof(CT) == 2) {
                    ((unsigned short*)C)[(size_t)row * N + col] = f2bf(v);
                } else {
                    ((float*)C)[(size_t)row * N + col] = v;
                }
            }
        }
    }
}

// ---- merged QKV projection: [4096][3072] = x @ [Wq;Wk;Wv]^T -----------------

__global__ __launch_bounds__(256) void gemm_qkv(
    const unsigned short* __restrict__ A,
    const unsigned short* __restrict__ Bm,
    unsigned short* __restrict__ Cqk,
    unsigned short* __restrict__ Vt)
{
    constexpr int BK = 32, K = 1024;
    __shared__ unsigned short As[128 * BK];
    __shared__ unsigned short Bs[128 * BK];

    const int tid  = threadIdx.x;
    const int lane = tid & 63;
    const int wid  = tid >> 6;
    const int wr = wid >> 1, wc = wid & 1;
    const int l15 = lane & 15, lhi = lane >> 4;
    const int tm = blockIdx.y * 128, tn = blockIdx.x * 128;

    f32x4 acc[4][4] = {};

    const int srow = (lane >> 2);
    const int scol = (lane & 3) * 8;

    for (int k0 = 0; k0 < K; k0 += BK) {
        __syncthreads();
        #pragma unroll
        for (int i = 0; i < 2; ++i) {
            int chunk = wid * 2 + i;
            int row = chunk * 16 + srow;
            gload_lds16(A  + (size_t)(tm + row) * K + k0 + scol, (void*)(As + chunk * 512));
            gload_lds16(Bm + (size_t)(tn + row) * K + k0 + scol, (void*)(Bs + chunk * 512));
        }
        __syncthreads();

        bf16x8 af[4], bfr[4];
        #pragma unroll
        for (int i = 0; i < 4; ++i)
            af[i] = *reinterpret_cast<const bf16x8*>(As + (wr * 64 + i * 16 + l15) * BK + lhi * 8);
        #pragma unroll
        for (int j = 0; j < 4; ++j)
            bfr[j] = *reinterpret_cast<const bf16x8*>(Bs + (wc * 64 + j * 16 + l15) * BK + lhi * 8);
        #pragma unroll
        for (int i = 0; i < 4; ++i)
            #pragma unroll
            for (int j = 0; j < 4; ++j)
                acc[i][j] = __builtin_amdgcn_mfma_f32_16x16x32_bf16(af[i], bfr[j], acc[i][j], 0, 0, 0);
    }

    const bool isV = (tn >= 2048);
    #pragma unroll
    for (int i = 0; i < 4; ++i) {
        #pragma unroll
        for (int j = 0; j < 4; ++j) {
            int col = tn + wc * 64 + j * 16 + l15;
            int row0 = tm + wr * 64 + i * 16 + lhi * 4;
            if (!isV) {
                #pragma unroll
                for (int r = 0; r < 4; ++r)
                    Cqk[(size_t)(row0 + r) * 2048 + col] = f2bf(acc[i][j][r]);
            } else {
                unsigned short t[4];
                #pragma unroll
                for (int r = 0; r < 4; ++r) t[r] = f2bf(acc[i][j][r]);
                *reinterpret_cast<uint2*>(Vt + (size_t)(col - 2048) * M_ + row0) =
                    *reinterpret_cast<const uint2*>(t);
            }
        }
    }
}

// ---- flash attention (causal), split-K, single-buffer software pipeline -----
// QK: [4096][2048] bf16 — Q cols 0..1023 (pre-scaled), K cols 1024..2047
// VT: [1024][4096] bf16 — row h*64+d, col b*2048+k
// grid 2048 x 256: block owns 32 q rows; wave w handles tiles kt=w, w+4, ...
// (static softmax => partials combine linearly). Per-wave single 8KB K/V
// buffer, but PIPELINED: next tile's K loads are issued right after this
// tile's QK ds_reads retire (lgkmcnt(0)+sched_barrier), V loads after the
// vf ds_reads — each load gets a full softmax/PV/QK phase of cover before
// its counted-vmcnt wait (T3/T4 per-wave). Zero extra LDS vs round 11.

__global__ __launch_bounds__(256, 4) void attn_kernel(
    const unsigned short* __restrict__ QK,
    const unsigned short* __restrict__ VT,
    unsigned short* __restrict__ Ctx)
{
    __shared__ unsigned short Ks[4][32 * 64];  // per-wave [kv][d], swz ^(row&7)
    __shared__ unsigned short Vs[4][64 * 32];  // per-wave [d][kv], swz ^((d>>1)&3)

    const int tid  = threadIdx.x;
    const int lane = tid & 63;
    const int wid  = tid >> 6;          // 0..3
    const int l31  = lane & 31;
    const int hi   = lane >> 5;

    // XCD-aware remap (lin%8 = XCD); heavy q-blocks first
    const int lin  = blockIdx.x;
    const int idx  = lin >> 3;          // 0..255
    const int bh   = (lin & 7) + 8 * (idx & 3);
    const int qb   = 63 - (idx >> 2);   // 0..63, heavy first
    const int b = bh >> 4, h = bh & 15;
    const size_t baseRow = (size_t)b * S_;
    const int qw = qb * 32;
    const int q  = qw + l31;

    // Q B-fragments (same 32 q rows for all 4 waves; pre-scaled at cast)
    bf16x8 qf[4];
    #pragma unroll
    for (int s = 0; s < 4; ++s)
        qf[s] = *reinterpret_cast<const bf16x8*>(
            QK + (baseRow + q) * 2048 + h * HD_ + s * 16 + hi * 8);

    float l = 0.0f;
    f32x16 oacc[2] = {};

    const int nkt = qb + 1;             // KV tiles of 32

    // staging indices (per-wave lane)
    const int kr  = lane >> 3;          // K: row-in-8-group
    const int ks  = lane & 7;           // K: 16B slot (8 per 128B row)
    const int vr  = lane >> 2;          // V: row-in-16-group
    const int vsl = lane & 3;           // V: 16B slot (4 per 64B row)

#define STAGE_K(kt_) do {                                                      \
    int k0_ = (kt_) * 32;                                                      \
    _Pragma("unroll")                                                          \
    for (int i_ = 0; i_ < 4; ++i_) {                                           \
        int krow_ = i_ * 8 + kr;                                               \
        int ksc_  = (ks ^ kr) * 8;                                             \
        gload_lds16(QK + (baseRow + k0_ + krow_) * 2048 + D_ + h * HD_ + ksc_, \
                    (void*)(&Ks[wid][i_ * 512]));                              \
    } } while (0)
#define STAGE_V(kt_) do {                                                      \
    int k0_ = (kt_) * 32;                                                      \
    _Pragma("unroll")                                                          \
    for (int i_ = 0; i_ < 4; ++i_) {                                           \
        int vrow_ = i_ * 16 + vr;                                              \
        int vsc_  = (vsl ^ ((vrow_ >> 1) & 3)) * 8;                            \
        gload_lds16(VT + (size_t)(h * HD_ + vrow_) * M_ + baseRow + k0_ + vsc_,\
                    (void*)(&Vs[wid][i_ * 512]));                              \
    } } while (0)

    if (wid < nkt) {
        STAGE_K(wid);                    // prologue: first tile in flight
        STAGE_V(wid);
        for (int kt = wid; kt < nkt; kt += 4) {
            const bool more = (kt + 4 < nkt);

            // K(cur) landed (V(cur) still in flight)
            asm volatile("s_waitcnt vmcnt(4)" ::: "memory");
            __builtin_amdgcn_sched_barrier(0);

            const unsigned short* Kc = &Ks[wid][0];

            // swapped QK^T: sc[row=kv local][col=q=l31]
            f32x16 sc = {};
            #pragma unroll
            for (int s = 0; s < 4; ++s) {
                int sl = (2 * s + hi) ^ (l31 & 7);
                bf16x8 kf = *reinterpret_cast<const bf16x8*>(Kc + l31 * 64 + sl * 8);
                sc = __builtin_amdgcn_mfma_f32_32x32x16_bf16(kf, qf[s], sc, 0, 0, 0);
            }

            // K ds_reads retired -> K buffer free: prefetch next K NOW
            asm volatile("s_waitcnt lgkmcnt(0)" ::: "memory");
            __builtin_amdgcn_sched_barrier(0);
            if (more) STAGE_K(kt + 4);   // covered by softmax+vf+PV below

            if (kt == qb) {   // diagonal tile: causal mask
                #pragma unroll
                for (int r = 0; r < 16; ++r) {
                    int kl = kt * 32 + (r & 3) + 8 * (r >> 2) + 4 * hi;
                    if (kl > q) sc[r] = -INFINITY;
                }
            }

            // static softmax (exp2 domain) -> packed bf16 P
            unsigned int g0, g1, g2, g3, g4, g5, g6, g7;
            float ps = 0.0f;
            {
                float e0, e1, e2, e3;
                e0=exp2f(sc[0]);  e1=exp2f(sc[1]);  e2=exp2f(sc[2]);  e3=exp2f(sc[3]);
                ps += (e0+e1)+(e2+e3); g0 = cvt_pk_bf16(e0,e1); g1 = cvt_pk_bf16(e2,e3);
                e0=exp2f(sc[4]);  e1=exp2f(sc[5]);  e2=exp2f(sc[6]);  e3=exp2f(sc[7]);
                ps += (e0+e1)+(e2+e3); g2 = cvt_pk_bf16(e0,e1); g3 = cvt_pk_bf16(e2,e3);
                e0=exp2f(sc[8]);  e1=exp2f(sc[9]);  e2=exp2f(sc[10]); e3=exp2f(sc[11]);
                ps += (e0+e1)+(e2+e3); g4 = cvt_pk_bf16(e0,e1); g5 = cvt_pk_bf16(e2,e3);
                e0=exp2f(sc[12]); e1=exp2f(sc[13]); e2=exp2f(sc[14]); e3=exp2f(sc[15]);
                ps += (e0+e1)+(e2+e3); g6 = cvt_pk_bf16(e0,e1); g7 = cvt_pk_bf16(e2,e3);
            }
            l += ps;

            // P -> A-fragments via permlane32_swap
            asm("v_permlane32_swap_b32 %0, %1" : "+v"(g0), "+v"(g2));
            asm("v_permlane32_swap_b32 %0, %1" : "+v"(g1), "+v"(g3));
            asm("v_permlane32_swap_b32 %0, %1" : "+v"(g4), "+v"(g6));
            asm("v_permlane32_swap_b32 %0, %1" : "+v"(g5), "+v"(g7));
            bf16x8 pa0 = __builtin_bit_cast(bf16x8, (u32x4){g0, g1, g2, g3});
            bf16x8 pa1 = __builtin_bit_cast(bf16x8, (u32x4){g4, g5, g6, g7});

            // V(cur) landed (K(next) may remain in flight)
            if (more) asm volatile("s_waitcnt vmcnt(4)" ::: "memory");
            else      asm volatile("s_waitcnt vmcnt(0)" ::: "memory");
            __builtin_amdgcn_sched_barrier(0);

            const unsigned short* Vc = &Vs[wid][0];
            bf16x8 vf[2][2];
            #pragma unroll
            for (int dt = 0; dt < 2; ++dt)
                #pragma unroll
                for (int s = 0; s < 2; ++s) {
                    int d = dt * 32 + l31;
                    int sl = (2 * s + hi) ^ ((d >> 1) & 3);
                    vf[dt][s] = *reinterpret_cast<const bf16x8*>(Vc + d * 32 + sl * 8);
                }

            // V ds_reads retired -> V buffer free: prefetch next V
            asm volatile("s_waitcnt lgkmcnt(0)" ::: "memory");
            __builtin_amdgcn_sched_barrier(0);
            if (more) STAGE_V(kt + 4);   // covered by PV + next QK + softmax

            // O += P · V   (pure MFMA cluster)
            __builtin_amdgcn_s_setprio(1);
            #pragma unroll
            for (int dt = 0; dt < 2; ++dt) {
                oacc[dt] = __builtin_amdgcn_mfma_f32_32x32x16_bf16(pa0, vf[dt][0], oacc[dt], 0, 0, 0);
                oacc[dt] = __builtin_amdgcn_mfma_f32_32x32x16_bf16(pa1, vf[dt][1], oacc[dt], 0, 0, 0);
            }
            __builtin_amdgcn_s_setprio(0);
        }
    }
#undef STAGE_K
#undef STAGE_V

    // ---- split-K combine: two phases reusing the 4KB per-wave buffers ----
    float* Olw = (float*)&Ks[wid][0];          // 32q x 32d f32 = 4KB
    float* Lpw = (float*)&Vs[wid][0];          // 32 f32
    float lc = l + __shfl_xor(l, 32, 64);
    if (hi == 0) Lpw[l31] = lc;

    const int cq = tid >> 3;
    const int cd = (tid & 7) * 4;
    float inv = 0.0f;
    #pragma unroll
    for (int ph = 0; ph < 2; ++ph) {
        __syncthreads();                       // prior reads of Ks/Vs complete
        #pragma unroll
        for (int r = 0; r < 16; ++r) {
            int qr = (r & 3) + 8 * (r >> 2) + 4 * hi;
            Olw[qr * 32 + l31] = oacc[ph][r];
        }
        __syncthreads();
        float s0 = 0, s1 = 0, s2 = 0, s3 = 0, lt = 0;
        #pragma unroll
        for (int w = 0; w < 4; ++w) {
            const float* O = (const float*)&Ks[w][0];
            f32x4 a = *reinterpret_cast<const f32x4*>(O + cq * 32 + cd);
            s0 += a[0]; s1 += a[1]; s2 += a[2]; s3 += a[3];
            if (ph == 0) lt += ((const float*)&Vs[w][0])[cq];
        }
        if (ph == 0) inv = 1.0f / lt;
        unsigned short o[4];
        o[0] = f2bf(s0 * inv); o[1] = f2bf(s1 * inv);
        o[2] = f2bf(s2 * inv); o[3] = f2bf(s3 * inv);
        *reinterpret_cast<uint2*>(
            Ctx + (baseRow + qw + cq) * D_ + h * HD_ + ph * 32 + cd) =
            *reinterpret_cast<const uint2*>(o);
    }
}

// ---- launch -----------------------------------------------------------------

extern "C" void kernel_launch(void* const* d_in, const int* in_sizes, int n_in,
                              void* d_out, int out_size, void* d_ws, size_t ws_size,
                              hipStream_t stream) {
    const float* x  = (const float*)d_in[0];
    const float* wq = (const float*)d_in[1];
    const float* wk = (const float*)d_in[2];
    const float* wv = (const float*)d_in[3];
    const float* wo = (const float*)d_in[4];
    const float* bo = (const float*)d_in[5];

    unsigned short* ws = (unsigned short*)d_ws;
    unsigned short* xb  = ws;                       // [4096][1024]  8 MB
    unsigned short* wqb = xb  + 4194304;            // wq|wk|wv stacked
    unsigned short* wob = wqb + 3145728;
    unsigned short* QKb = wob + 1048576;            // [4096][2048] 16 MB
    unsigned short* VT  = QKb + 8388608;            // [1024][4096]  8 MB
    unsigned short* Cx  = VT  + 4194304;            // [4096][1024]  8 MB

    cast_all<<<4096, 256, 0, stream>>>(x, wq, wk, wv, wo, xb);

    // merged QKV projection (V written transposed)
    gemm_qkv<<<dim3(24, 32), 256, 0, stream>>>(xb, wqb, QKb, VT);

    // causal flash attention, split-K over 4 waves, pipelined single buffer
    attn_kernel<<<2048, 256, 0, stream>>>(QKb, VT, Cx);

    // out = ctx @ Wo^T + b_out  (fp32 out)
    gemm_bt<true, float><<<dim3(8, 32), 256, 0, stream>>>(
        Cx, wob, (float*)d_out, bo, M_, D_, D_);
}

// Round 13
// 106.871 us; speedup vs baseline: 1.3233x; 1.0204x over previous
//
#include <hip/hip_runtime.h>
#include <stdint.h>

// Problem constants
#define B_  2
#define S_  2048
#define D_  1024
#define H_  16
#define HD_ 64
#define M_  (B_*S_)   // 4096 rows

typedef __attribute__((ext_vector_type(8)))  short bf16x8;   // 8 bf16 in 4 VGPRs
typedef __attribute__((ext_vector_type(4)))  float f32x4;
typedef __attribute__((ext_vector_type(16))) float f32x16;
typedef __attribute__((ext_vector_type(4)))  unsigned int u32x4;

// ---- helpers ----------------------------------------------------------------

__device__ __forceinline__ unsigned short f2bf(float f) {
    unsigned int u = __float_as_uint(f);
    unsigned int r = (u + 0x7fffu + ((u >> 16) & 1u)) >> 16;
    return (unsigned short)r;
}

__device__ __forceinline__ unsigned int cvt_pk_bf16(float lo, float hi) {
    unsigned int r;
    asm("v_cvt_pk_bf16_f32 %0, %1, %2" : "=v"(r) : "v"(lo), "v"(hi));
    return r;
}

__device__ __forceinline__ void gload_lds16(const void* g, void* l) {
    __builtin_amdgcn_global_load_lds(
        (const __attribute__((address_space(1))) unsigned int*)g,
        (__attribute__((address_space(3))) unsigned int*)l,
        16, 0, 0);
}

// ---- fused fp32 -> bf16 cast; Wq/Wk pre-scaled by sqrt(log2(e)/8) -----------

__global__ __launch_bounds__(256) void cast_all(
    const float* __restrict__ x,
    const float* __restrict__ wq, const float* __restrict__ wk,
    const float* __restrict__ wv, const float* __restrict__ wo,
    unsigned short* __restrict__ dst)
{
    int b = blockIdx.x;
    const float* src;
    size_t soff, doff;
    float sc = 1.0f;
    if (b < 2048) {
        src = x; soff = (size_t)b * 2048; doff = soff;
    } else {
        int r  = (b - 2048) >> 9;
        int lb = (b - 2048) & 511;
        src = (r == 0) ? wq : (r == 1) ? wk : (r == 2) ? wv : wo;
        if (r <= 1) sc = 0.4246609093670877f;   // sqrt(log2(e)/sqrt(64))
        soff = (size_t)lb * 2048;
        doff = (size_t)4194304 + (size_t)r * 1048576 + soff;
    }
    int idx = threadIdx.x * 8;
    float4 a = *reinterpret_cast<const float4*>(src + soff + idx);
    float4 c = *reinterpret_cast<const float4*>(src + soff + idx + 4);
    unsigned short t[8];
    t[0]=f2bf(a.x*sc); t[1]=f2bf(a.y*sc); t[2]=f2bf(a.z*sc); t[3]=f2bf(a.w*sc);
    t[4]=f2bf(c.x*sc); t[5]=f2bf(c.y*sc); t[6]=f2bf(c.z*sc); t[7]=f2bf(c.w*sc);
    *reinterpret_cast<uint4*>(dst + doff + idx) = *reinterpret_cast<const uint4*>(t);
}

// ---- merged QKV projection: [4096][3072] = x @ [Wq;Wk;Wv]^T -----------------

__global__ __launch_bounds__(256) void gemm_qkv(
    const unsigned short* __restrict__ A,
    const unsigned short* __restrict__ Bm,
    unsigned short* __restrict__ Cqk,
    unsigned short* __restrict__ Vt)
{
    constexpr int BK = 32, K = 1024;
    __shared__ unsigned short As[128 * BK];
    __shared__ unsigned short Bs[128 * BK];

    const int tid  = threadIdx.x;
    const int lane = tid & 63;
    const int wid  = tid >> 6;
    const int wr = wid >> 1, wc = wid & 1;
    const int l15 = lane & 15, lhi = lane >> 4;
    const int tm = blockIdx.y * 128, tn = blockIdx.x * 128;

    f32x4 acc[4][4] = {};

    const int srow = (lane >> 2);
    const int scol = (lane & 3) * 8;

    for (int k0 = 0; k0 < K; k0 += BK) {
        __syncthreads();
        #pragma unroll
        for (int i = 0; i < 2; ++i) {
            int chunk = wid * 2 + i;
            int row = chunk * 16 + srow;
            gload_lds16(A  + (size_t)(tm + row) * K + k0 + scol, (void*)(As + chunk * 512));
            gload_lds16(Bm + (size_t)(tn + row) * K + k0 + scol, (void*)(Bs + chunk * 512));
        }
        __syncthreads();

        bf16x8 af[4], bfr[4];
        #pragma unroll
        for (int i = 0; i < 4; ++i)
            af[i] = *reinterpret_cast<const bf16x8*>(As + (wr * 64 + i * 16 + l15) * BK + lhi * 8);
        #pragma unroll
        for (int j = 0; j < 4; ++j)
            bfr[j] = *reinterpret_cast<const bf16x8*>(Bs + (wc * 64 + j * 16 + l15) * BK + lhi * 8);
        #pragma unroll
        for (int i = 0; i < 4; ++i)
            #pragma unroll
            for (int j = 0; j < 4; ++j)
                acc[i][j] = __builtin_amdgcn_mfma_f32_16x16x32_bf16(af[i], bfr[j], acc[i][j], 0, 0, 0);
    }

    const bool isV = (tn >= 2048);
    #pragma unroll
    for (int i = 0; i < 4; ++i) {
        #pragma unroll
        for (int j = 0; j < 4; ++j) {
            int col = tn + wc * 64 + j * 16 + l15;
            int row0 = tm + wr * 64 + i * 16 + lhi * 4;
            if (!isV) {
                #pragma unroll
                for (int r = 0; r < 4; ++r)
                    Cqk[(size_t)(row0 + r) * 2048 + col] = f2bf(acc[i][j][r]);
            } else {
                unsigned short t[4];
                #pragma unroll
                for (int r = 0; r < 4; ++r) t[r] = f2bf(acc[i][j][r]);
                *reinterpret_cast<uint2*>(Vt + (size_t)(col - 2048) * M_ + row0) =
                    *reinterpret_cast<const uint2*>(t);
            }
        }
    }
}

// ---- out-projection GEMM: [4096][1024] = Cx @ Wo^T + b, 128x64 tiles --------
// grid (16, 32) = 512 blocks (2+/CU vs 1/CU at 128x128). 4 waves 2x2; each
// wave 64x32 = 4x2 frags. LDS 12KB.

__global__ __launch_bounds__(256) void gemm_out(
    const unsigned short* __restrict__ A,
    const unsigned short* __restrict__ Bm,
    float* __restrict__ C,
    const float* __restrict__ bias)
{
    constexpr int BK = 32, K = 1024, N = 1024;
    __shared__ unsigned short As[128 * BK];
    __shared__ unsigned short Bs[64 * BK];

    const int tid  = threadIdx.x;
    const int lane = tid & 63;
    const int wid  = tid >> 6;
    const int wr = wid >> 1, wc = wid & 1;
    const int l15 = lane & 15, lhi = lane >> 4;
    const int tm = blockIdx.y * 128, tn = blockIdx.x * 64;

    f32x4 acc[4][2] = {};

    const int srow = (lane >> 2);
    const int scol = (lane & 3) * 8;

    for (int k0 = 0; k0 < K; k0 += BK) {
        __syncthreads();
        #pragma unroll
        for (int i = 0; i < 2; ++i) {
            int chunk = wid * 2 + i;
            int row = chunk * 16 + srow;
            gload_lds16(A + (size_t)(tm + row) * K + k0 + scol, (void*)(As + chunk * 512));
        }
        gload_lds16(Bm + (size_t)(tn + wid * 16 + srow) * K + k0 + scol, (void*)(Bs + wid * 512));
        __syncthreads();

        bf16x8 af[4], bfr[2];
        #pragma unroll
        for (int i = 0; i < 4; ++i)
            af[i] = *reinterpret_cast<const bf16x8*>(As + (wr * 64 + i * 16 + l15) * BK + lhi * 8);
        #pragma unroll
        for (int j = 0; j < 2; ++j)
            bfr[j] = *reinterpret_cast<const bf16x8*>(Bs + (wc * 32 + j * 16 + l15) * BK + lhi * 8);
        #pragma unroll
        for (int i = 0; i < 4; ++i)
            #pragma unroll
            for (int j = 0; j < 2; ++j)
                acc[i][j] = __builtin_amdgcn_mfma_f32_16x16x32_bf16(af[i], bfr[j], acc[i][j], 0, 0, 0);
    }

    #pragma unroll
    for (int i = 0; i < 4; ++i) {
        #pragma unroll
        for (int j = 0; j < 2; ++j) {
            int col = tn + wc * 32 + j * 16 + l15;
            float bv = bias[col];
            #pragma unroll
            for (int r = 0; r < 4; ++r) {
                int row = tm + wr * 64 + i * 16 + lhi * 4 + r;
                C[(size_t)row * N + col] = acc[i][j][r] + bv;
            }
        }
    }
}

// ---- flash attention (causal), paired q-tiles, balanced blocks --------------
// QK: [4096][2048] bf16 — Q cols 0..1023 (pre-scaled), K cols 1024..2047
// VT: [1024][4096] bf16 — row h*64+d, col b*2048+k
// grid 1024 x 256: block handles TWO complementary q-tiles (qb, 63-qb) —
// waves 0-1 split-K tile A, waves 2-3 tile B => every block does exactly
// 65 wave-tiles (constant duration, no drain imbalance). Per-wave single
// 8KB K/V buffer, software-pipelined (prefetch stride 2, counted vmcnt).
// Static softmax; per-pair 2-wave combine epilogue.

__global__ __launch_bounds__(256, 4) void attn_kernel(
    const unsigned short* __restrict__ QK,
    const unsigned short* __restrict__ VT,
    unsigned short* __restrict__ Ctx)
{
    __shared__ unsigned short Ks[4][32 * 64];  // per-wave [kv][d], swz ^(row&7)
    __shared__ unsigned short Vs[4][64 * 32];  // per-wave [d][kv], swz ^((d>>1)&3)

    const int tid  = threadIdx.x;
    const int lane = tid & 63;
    const int wid  = tid >> 6;          // 0..3
    const int l31  = lane & 31;
    const int hi   = lane >> 5;
    const int pw   = wid >> 1;          // 0: q-tile A, 1: q-tile B
    const int sw   = wid & 1;           // split-K index within pair

    // XCD-aware remap (lin%8 = XCD)
    const int lin  = blockIdx.x;        // 0..1023
    const int idx  = lin >> 3;          // 0..127
    const int bh   = (lin & 7) + 8 * (idx & 3);
    const int pidx = idx >> 2;          // 0..31
    const int qb   = pw ? (63 - pidx) : pidx;   // complementary pair
    const int b = bh >> 4, h = bh & 15;
    const size_t baseRow = (size_t)b * S_;
    const int qw = qb * 32;
    const int q  = qw + l31;

    // Q B-fragments (pre-scaled at cast)
    bf16x8 qf[4];
    #pragma unroll
    for (int s = 0; s < 4; ++s)
        qf[s] = *reinterpret_cast<const bf16x8*>(
            QK + (baseRow + q) * 2048 + h * HD_ + s * 16 + hi * 8);

    float l = 0.0f;
    f32x16 oacc[2] = {};

    // staging indices (per-wave lane)
    const int kr  = lane >> 3;          // K: row-in-8-group
    const int ks  = lane & 7;           // K: 16B slot (8 per 128B row)
    const int vr  = lane >> 2;          // V: row-in-16-group
    const int vsl = lane & 3;           // V: 16B slot (4 per 64B row)

#define STAGE_K(kt_) do {                                                      \
    int k0_ = (kt_) * 32;                                                      \
    _Pragma("unroll")                                                          \
    for (int i_ = 0; i_ < 4; ++i_) {                                           \
        int krow_ = i_ * 8 + kr;                                               \
        int ksc_  = (ks ^ kr) * 8;                                             \
        gload_lds16(QK + (baseRow + k0_ + krow_) * 2048 + D_ + h * HD_ + ksc_, \
                    (void*)(&Ks[wid][i_ * 512]));                              \
    } } while (0)
#define STAGE_V(kt_) do {                                                      \
    int k0_ = (kt_) * 32;                                                      \
    _Pragma("unroll")                                                          \
    for (int i_ = 0; i_ < 4; ++i_) {                                           \
        int vrow_ = i_ * 16 + vr;                                              \
        int vsc_  = (vsl ^ ((vrow_ >> 1) & 3)) * 8;                            \
        gload_lds16(VT + (size_t)(h * HD_ + vrow_) * M_ + baseRow + k0_ + vsc_,\
                    (void*)(&Vs[wid][i_ * 512]));                              \
    } } while (0)

    if (sw <= qb) {
        STAGE_K(sw);                     // prologue: first tile in flight
        STAGE_V(sw);
        for (int kt = sw; kt <= qb; kt += 2) {
            const bool more = (kt + 2 <= qb);

            // K(cur) landed (V(cur) still in flight)
            asm volatile("s_waitcnt vmcnt(4)" ::: "memory");
            __builtin_amdgcn_sched_barrier(0);

            const unsigned short* Kc = &Ks[wid][0];

            // swapped QK^T: sc[row=kv local][col=q=l31]
            f32x16 sc = {};
            #pragma unroll
            for (int s = 0; s < 4; ++s) {
                int sl = (2 * s + hi) ^ (l31 & 7);
                bf16x8 kf = *reinterpret_cast<const bf16x8*>(Kc + l31 * 64 + sl * 8);
                sc = __builtin_amdgcn_mfma_f32_32x32x16_bf16(kf, qf[s], sc, 0, 0, 0);
            }

            // K ds_reads retired -> K buffer free: prefetch next K
            asm volatile("s_waitcnt lgkmcnt(0)" ::: "memory");
            __builtin_amdgcn_sched_barrier(0);
            if (more) STAGE_K(kt + 2);

            if (kt == qb) {   // diagonal tile: causal mask
                #pragma unroll
                for (int r = 0; r < 16; ++r) {
                    int kl = kt * 32 + (r & 3) + 8 * (r >> 2) + 4 * hi;
                    if (kl > q) sc[r] = -INFINITY;
                }
            }

            // static softmax (exp2 domain) -> packed bf16 P
            unsigned int g0, g1, g2, g3, g4, g5, g6, g7;
            float ps = 0.0f;
            {
                float e0, e1, e2, e3;
                e0=exp2f(sc[0]);  e1=exp2f(sc[1]);  e2=exp2f(sc[2]);  e3=exp2f(sc[3]);
                ps += (e0+e1)+(e2+e3); g0 = cvt_pk_bf16(e0,e1); g1 = cvt_pk_bf16(e2,e3);
                e0=exp2f(sc[4]);  e1=exp2f(sc[5]);  e2=exp2f(sc[6]);  e3=exp2f(sc[7]);
                ps += (e0+e1)+(e2+e3); g2 = cvt_pk_bf16(e0,e1); g3 = cvt_pk_bf16(e2,e3);
                e0=exp2f(sc[8]);  e1=exp2f(sc[9]);  e2=exp2f(sc[10]); e3=exp2f(sc[11]);
                ps += (e0+e1)+(e2+e3); g4 = cvt_pk_bf16(e0,e1); g5 = cvt_pk_bf16(e2,e3);
                e0=exp2f(sc[12]); e1=exp2f(sc[13]); e2=exp2f(sc[14]); e3=exp2f(sc[15]);
                ps += (e0+e1)+(e2+e3); g6 = cvt_pk_bf16(e0,e1); g7 = cvt_pk_bf16(e2,e3);
            }
            l += ps;

            // P -> A-fragments via permlane32_swap
            asm("v_permlane32_swap_b32 %0, %1" : "+v"(g0), "+v"(g2));
            asm("v_permlane32_swap_b32 %0, %1" : "+v"(g1), "+v"(g3));
            asm("v_permlane32_swap_b32 %0, %1" : "+v"(g4), "+v"(g6));
            asm("v_permlane32_swap_b32 %0, %1" : "+v"(g5), "+v"(g7));
            bf16x8 pa0 = __builtin_bit_cast(bf16x8, (u32x4){g0, g1, g2, g3});
            bf16x8 pa1 = __builtin_bit_cast(bf16x8, (u32x4){g4, g5, g6, g7});

            // V(cur) landed (K(next) may remain in flight)
            if (more) asm volatile("s_waitcnt vmcnt(4)" ::: "memory");
            else      asm volatile("s_waitcnt vmcnt(0)" ::: "memory");
            __builtin_amdgcn_sched_barrier(0);

            const unsigned short* Vc = &Vs[wid][0];
            bf16x8 vf[2][2];
            #pragma unroll
            for (int dt = 0; dt < 2; ++dt)
                #pragma unroll
                for (int s = 0; s < 2; ++s) {
                    int d = dt * 32 + l31;
                    int sl = (2 * s + hi) ^ ((d >> 1) & 3);
                    vf[dt][s] = *reinterpret_cast<const bf16x8*>(Vc + d * 32 + sl * 8);
                }

            // V ds_reads retired -> V buffer free: prefetch next V
            asm volatile("s_waitcnt lgkmcnt(0)" ::: "memory");
            __builtin_amdgcn_sched_barrier(0);
            if (more) STAGE_V(kt + 2);

            // O += P · V   (pure MFMA cluster)
            __builtin_amdgcn_s_setprio(1);
            #pragma unroll
            for (int dt = 0; dt < 2; ++dt) {
                oacc[dt] = __builtin_amdgcn_mfma_f32_32x32x16_bf16(pa0, vf[dt][0], oacc[dt], 0, 0, 0);
                oacc[dt] = __builtin_amdgcn_mfma_f32_32x32x16_bf16(pa1, vf[dt][1], oacc[dt], 0, 0, 0);
            }
            __builtin_amdgcn_s_setprio(0);
        }
    }
#undef STAGE_K
#undef STAGE_V

    // ---- per-pair 2-wave combine (two phases reusing 4KB buffers) ----
    float* Olw = (float*)&Ks[wid][0];          // 32q x 32d f32 = 4KB
    float* Lpw = (float*)&Vs[wid][0];          // 32 f32
    float lc = l + __shfl_xor(l, 32, 64);
    if (hi == 0) Lpw[l31] = lc;

    const int p  = tid >> 7;                   // pair index 0/1
    const int t  = tid & 127;
    const int cq = t >> 2;                     // 0..31
    const int cd = (t & 3) * 8;                // 0,8,16,24
    const int qwp = (p ? (63 - pidx) : pidx) * 32;
    float inv = 0.0f;
    #pragma unroll
    for (int ph = 0; ph < 2; ++ph) {
        __syncthreads();                       // prior reads of Ks/Vs complete
        #pragma unroll
        for (int r = 0; r < 16; ++r) {
            int qr = (r & 3) + 8 * (r >> 2) + 4 * hi;
            Olw[qr * 32 + l31] = oacc[ph][r];
        }
        __syncthreads();
        float s0 = 0, s1 = 0, s2 = 0, s3 = 0;
        float s4 = 0, s5 = 0, s6 = 0, s7 = 0;
        float lt = 0;
        #pragma unroll
        for (int w = 2 * p; w < 2 * p + 2; ++w) {
            const float* O = (const float*)&Ks[w][0];
            f32x4 a = *reinterpret_cast<const f32x4*>(O + cq * 32 + cd);
            f32x4 c = *reinterpret_cast<const f32x4*>(O + cq * 32 + cd + 4);
            s0 += a[0]; s1 += a[1]; s2 += a[2]; s3 += a[3];
            s4 += c[0]; s5 += c[1]; s6 += c[2]; s7 += c[3];
            if (ph == 0) lt += ((const float*)&Vs[w][0])[cq];
        }
        if (ph == 0) inv = 1.0f / lt;
        unsigned short o[8];
        o[0]=f2bf(s0*inv); o[1]=f2bf(s1*inv); o[2]=f2bf(s2*inv); o[3]=f2bf(s3*inv);
        o[4]=f2bf(s4*inv); o[5]=f2bf(s5*inv); o[6]=f2bf(s6*inv); o[7]=f2bf(s7*inv);
        *reinterpret_cast<uint4*>(
            Ctx + (baseRow + qwp + cq) * D_ + h * HD_ + ph * 32 + cd) =
            *reinterpret_cast<const uint4*>(o);
    }
}

// ---- launch -----------------------------------------------------------------

extern "C" void kernel_launch(void* const* d_in, const int* in_sizes, int n_in,
                              void* d_out, int out_size, void* d_ws, size_t ws_size,
                              hipStream_t stream) {
    const float* x  = (const float*)d_in[0];
    const float* wq = (const float*)d_in[1];
    const float* wk = (const float*)d_in[2];
    const float* wv = (const float*)d_in[3];
    const float* wo = (const float*)d_in[4];
    const float* bo = (const float*)d_in[5];

    unsigned short* ws = (unsigned short*)d_ws;
    unsigned short* xb  = ws;                       // [4096][1024]  8 MB
    unsigned short* wqb = xb  + 4194304;            // wq|wk|wv stacked
    unsigned short* wob = wqb + 3145728;
    unsigned short* QKb = wob + 1048576;            // [4096][2048] 16 MB
    unsigned short* VT  = QKb + 8388608;            // [1024][4096]  8 MB
    unsigned short* Cx  = VT  + 4194304;            // [4096][1024]  8 MB

    cast_all<<<4096, 256, 0, stream>>>(x, wq, wk, wv, wo, xb);

    // merged QKV projection (V written transposed)
    gemm_qkv<<<dim3(24, 32), 256, 0, stream>>>(xb, wqb, QKb, VT);

    // causal flash attention, paired q-tiles (constant block duration)
    attn_kernel<<<1024, 256, 0, stream>>>(QKb, VT, Cx);

    // out = ctx @ Wo^T + b_out  (fp32 out), 128x64 tiles, 512 blocks
    gemm_out<<<dim3(16, 32), 256, 0, stream>>>(Cx, wob, (float*)d_out, bo);
}

// Round 14
// 102.898 us; speedup vs baseline: 1.3744x; 1.0386x over previous
//
#include <hip/hip_runtime.h>
#include <stdint.h>

// Problem constants
#define B_  2
#define S_  2048
#define D_  1024
#define H_  16
#define HD_ 64
#define M_  (B_*S_)   // 4096 rows

typedef __attribute__((ext_vector_type(8)))  short bf16x8;   // 8 bf16 in 4 VGPRs
typedef __attribute__((ext_vector_type(4)))  float f32x4;
typedef __attribute__((ext_vector_type(16))) float f32x16;
typedef __attribute__((ext_vector_type(4)))  unsigned int u32x4;

// ---- helpers ----------------------------------------------------------------

__device__ __forceinline__ unsigned short f2bf(float f) {
    unsigned int u = __float_as_uint(f);
    unsigned int r = (u + 0x7fffu + ((u >> 16) & 1u)) >> 16;
    return (unsigned short)r;
}

__device__ __forceinline__ unsigned int cvt_pk_bf16(float lo, float hi) {
    unsigned int r;
    asm("v_cvt_pk_bf16_f32 %0, %1, %2" : "=v"(r) : "v"(lo), "v"(hi));
    return r;
}

__device__ __forceinline__ void gload_lds16(const void* g, void* l) {
    __builtin_amdgcn_global_load_lds(
        (const __attribute__((address_space(1))) unsigned int*)g,
        (__attribute__((address_space(3))) unsigned int*)l,
        16, 0, 0);
}

// ---- fused fp32 -> bf16 cast; Wq/Wk pre-scaled by sqrt(log2(e)/8) -----------

__global__ __launch_bounds__(256) void cast_all(
    const float* __restrict__ x,
    const float* __restrict__ wq, const float* __restrict__ wk,
    const float* __restrict__ wv, const float* __restrict__ wo,
    unsigned short* __restrict__ dst)
{
    int b = blockIdx.x;
    const float* src;
    size_t soff, doff;
    float sc = 1.0f;
    if (b < 2048) {
        src = x; soff = (size_t)b * 2048; doff = soff;
    } else {
        int r  = (b - 2048) >> 9;
        int lb = (b - 2048) & 511;
        src = (r == 0) ? wq : (r == 1) ? wk : (r == 2) ? wv : wo;
        if (r <= 1) sc = 0.4246609093670877f;   // sqrt(log2(e)/sqrt(64))
        soff = (size_t)lb * 2048;
        doff = (size_t)4194304 + (size_t)r * 1048576 + soff;
    }
    int idx = threadIdx.x * 8;
    float4 a = *reinterpret_cast<const float4*>(src + soff + idx);
    float4 c = *reinterpret_cast<const float4*>(src + soff + idx + 4);
    unsigned short t[8];
    t[0]=f2bf(a.x*sc); t[1]=f2bf(a.y*sc); t[2]=f2bf(a.z*sc); t[3]=f2bf(a.w*sc);
    t[4]=f2bf(c.x*sc); t[5]=f2bf(c.y*sc); t[6]=f2bf(c.z*sc); t[7]=f2bf(c.w*sc);
    *reinterpret_cast<uint4*>(dst + doff + idx) = *reinterpret_cast<const uint4*>(t);
}

// ---- merged QKV projection: [4096][3072] = x @ [Wq;Wk;Wv]^T -----------------
// 1D grid 768, XCD-chunked bijective swizzle: wgid=(lin%8)*96+lin/8 — each
// XCD gets 96 consecutive tiles (4 A-panels x 24 tn) -> A/B panel reuse in L2.

__global__ __launch_bounds__(256) void gemm_qkv(
    const unsigned short* __restrict__ A,
    const unsigned short* __restrict__ Bm,
    unsigned short* __restrict__ Cqk,
    unsigned short* __restrict__ Vt)
{
    constexpr int BK = 32, K = 1024;
    __shared__ unsigned short As[128 * BK];
    __shared__ unsigned short Bs[128 * BK];

    const int tid  = threadIdx.x;
    const int lane = tid & 63;
    const int wid  = tid >> 6;
    const int wr = wid >> 1, wc = wid & 1;
    const int l15 = lane & 15, lhi = lane >> 4;

    const int lin  = blockIdx.x;                 // 0..767
    const int wgid = (lin & 7) * 96 + (lin >> 3);
    const int tm = (wgid / 24) * 128, tn = (wgid % 24) * 128;

    f32x4 acc[4][4] = {};

    const int srow = (lane >> 2);
    const int scol = (lane & 3) * 8;

    for (int k0 = 0; k0 < K; k0 += BK) {
        __syncthreads();
        #pragma unroll
        for (int i = 0; i < 2; ++i) {
            int chunk = wid * 2 + i;
            int row = chunk * 16 + srow;
            gload_lds16(A  + (size_t)(tm + row) * K + k0 + scol, (void*)(As + chunk * 512));
            gload_lds16(Bm + (size_t)(tn + row) * K + k0 + scol, (void*)(Bs + chunk * 512));
        }
        __syncthreads();

        bf16x8 af[4], bfr[4];
        #pragma unroll
        for (int i = 0; i < 4; ++i)
            af[i] = *reinterpret_cast<const bf16x8*>(As + (wr * 64 + i * 16 + l15) * BK + lhi * 8);
        #pragma unroll
        for (int j = 0; j < 4; ++j)
            bfr[j] = *reinterpret_cast<const bf16x8*>(Bs + (wc * 64 + j * 16 + l15) * BK + lhi * 8);
        #pragma unroll
        for (int i = 0; i < 4; ++i)
            #pragma unroll
            for (int j = 0; j < 4; ++j)
                acc[i][j] = __builtin_amdgcn_mfma_f32_16x16x32_bf16(af[i], bfr[j], acc[i][j], 0, 0, 0);
    }

    const bool isV = (tn >= 2048);
    #pragma unroll
    for (int i = 0; i < 4; ++i) {
        #pragma unroll
        for (int j = 0; j < 4; ++j) {
            int col = tn + wc * 64 + j * 16 + l15;
            int row0 = tm + wr * 64 + i * 16 + lhi * 4;
            if (!isV) {
                #pragma unroll
                for (int r = 0; r < 4; ++r)
                    Cqk[(size_t)(row0 + r) * 2048 + col] = f2bf(acc[i][j][r]);
            } else {
                unsigned short t[4];
                #pragma unroll
                for (int r = 0; r < 4; ++r) t[r] = f2bf(acc[i][j][r]);
                *reinterpret_cast<uint2*>(Vt + (size_t)(col - 2048) * M_ + row0) =
                    *reinterpret_cast<const uint2*>(t);
            }
        }
    }
}

// ---- out-projection GEMM: [4096][1024] = Cx @ Wo^T + b, 128x64 tiles --------
// 1D grid 512, XCD-chunked: wgid=(lin%8)*64+lin/8 (64 tiles/XCD: 4 A-panels).

__global__ __launch_bounds__(256) void gemm_out(
    const unsigned short* __restrict__ A,
    const unsigned short* __restrict__ Bm,
    float* __restrict__ C,
    const float* __restrict__ bias)
{
    constexpr int BK = 32, K = 1024, N = 1024;
    __shared__ unsigned short As[128 * BK];
    __shared__ unsigned short Bs[64 * BK];

    const int tid  = threadIdx.x;
    const int lane = tid & 63;
    const int wid  = tid >> 6;
    const int wr = wid >> 1, wc = wid & 1;
    const int l15 = lane & 15, lhi = lane >> 4;

    const int lin  = blockIdx.x;                 // 0..511
    const int wgid = (lin & 7) * 64 + (lin >> 3);
    const int tm = (wgid >> 4) * 128, tn = (wgid & 15) * 64;

    f32x4 acc[4][2] = {};

    const int srow = (lane >> 2);
    const int scol = (lane & 3) * 8;

    for (int k0 = 0; k0 < K; k0 += BK) {
        __syncthreads();
        #pragma unroll
        for (int i = 0; i < 2; ++i) {
            int chunk = wid * 2 + i;
            int row = chunk * 16 + srow;
            gload_lds16(A + (size_t)(tm + row) * K + k0 + scol, (void*)(As + chunk * 512));
        }
        gload_lds16(Bm + (size_t)(tn + wid * 16 + srow) * K + k0 + scol, (void*)(Bs + wid * 512));
        __syncthreads();

        bf16x8 af[4], bfr[2];
        #pragma unroll
        for (int i = 0; i < 4; ++i)
            af[i] = *reinterpret_cast<const bf16x8*>(As + (wr * 64 + i * 16 + l15) * BK + lhi * 8);
        #pragma unroll
        for (int j = 0; j < 2; ++j)
            bfr[j] = *reinterpret_cast<const bf16x8*>(Bs + (wc * 32 + j * 16 + l15) * BK + lhi * 8);
        #pragma unroll
        for (int i = 0; i < 4; ++i)
            #pragma unroll
            for (int j = 0; j < 2; ++j)
                acc[i][j] = __builtin_amdgcn_mfma_f32_16x16x32_bf16(af[i], bfr[j], acc[i][j], 0, 0, 0);
    }

    #pragma unroll
    for (int i = 0; i < 4; ++i) {
        #pragma unroll
        for (int j = 0; j < 2; ++j) {
            int col = tn + wc * 32 + j * 16 + l15;
            float bv = bias[col];
            #pragma unroll
            for (int r = 0; r < 4; ++r) {
                int row = tm + wr * 64 + i * 16 + lhi * 4 + r;
                C[(size_t)row * N + col] = acc[i][j][r] + bv;
            }
        }
    }
}

// ---- flash attention (causal), split-K, single-buffer software pipeline -----
// (round-12 structure, measured 40.0 us — round-13 pairing regressed it)
// QK: [4096][2048] bf16 — Q cols 0..1023 (pre-scaled), K cols 1024..2047
// VT: [1024][4096] bf16 — row h*64+d, col b*2048+k
// grid 2048 x 256: block owns 32 q rows; wave w handles tiles kt=w, w+4, ...

__global__ __launch_bounds__(256, 4) void attn_kernel(
    const unsigned short* __restrict__ QK,
    const unsigned short* __restrict__ VT,
    unsigned short* __restrict__ Ctx)
{
    __shared__ unsigned short Ks[4][32 * 64];  // per-wave [kv][d], swz ^(row&7)
    __shared__ unsigned short Vs[4][64 * 32];  // per-wave [d][kv], swz ^((d>>1)&3)

    const int tid  = threadIdx.x;
    const int lane = tid & 63;
    const int wid  = tid >> 6;          // 0..3
    const int l31  = lane & 31;
    const int hi   = lane >> 5;

    // XCD-aware remap (lin%8 = XCD); heavy q-blocks first
    const int lin  = blockIdx.x;
    const int idx  = lin >> 3;          // 0..255
    const int bh   = (lin & 7) + 8 * (idx & 3);
    const int qb   = 63 - (idx >> 2);   // 0..63, heavy first
    const int b = bh >> 4, h = bh & 15;
    const size_t baseRow = (size_t)b * S_;
    const int qw = qb * 32;
    const int q  = qw + l31;

    // Q B-fragments (same 32 q rows for all 4 waves; pre-scaled at cast)
    bf16x8 qf[4];
    #pragma unroll
    for (int s = 0; s < 4; ++s)
        qf[s] = *reinterpret_cast<const bf16x8*>(
            QK + (baseRow + q) * 2048 + h * HD_ + s * 16 + hi * 8);

    float l = 0.0f;
    f32x16 oacc[2] = {};

    const int nkt = qb + 1;             // KV tiles of 32

    // staging indices (per-wave lane)
    const int kr  = lane >> 3;          // K: row-in-8-group
    const int ks  = lane & 7;           // K: 16B slot (8 per 128B row)
    const int vr  = lane >> 2;          // V: row-in-16-group
    const int vsl = lane & 3;           // V: 16B slot (4 per 64B row)

#define STAGE_K(kt_) do {                                                      \
    int k0_ = (kt_) * 32;                                                      \
    _Pragma("unroll")                                                          \
    for (int i_ = 0; i_ < 4; ++i_) {                                           \
        int krow_ = i_ * 8 + kr;                                               \
        int ksc_  = (ks ^ kr) * 8;                                             \
        gload_lds16(QK + (baseRow + k0_ + krow_) * 2048 + D_ + h * HD_ + ksc_, \
                    (void*)(&Ks[wid][i_ * 512]));                              \
    } } while (0)
#define STAGE_V(kt_) do {                                                      \
    int k0_ = (kt_) * 32;                                                      \
    _Pragma("unroll")                                                          \
    for (int i_ = 0; i_ < 4; ++i_) {                                           \
        int vrow_ = i_ * 16 + vr;                                              \
        int vsc_  = (vsl ^ ((vrow_ >> 1) & 3)) * 8;                            \
        gload_lds16(VT + (size_t)(h * HD_ + vrow_) * M_ + baseRow + k0_ + vsc_,\
                    (void*)(&Vs[wid][i_ * 512]));                              \
    } } while (0)

    if (wid < nkt) {
        STAGE_K(wid);                    // prologue: first tile in flight
        STAGE_V(wid);
        for (int kt = wid; kt < nkt; kt += 4) {
            const bool more = (kt + 4 < nkt);

            // K(cur) landed (V(cur) still in flight)
            asm volatile("s_waitcnt vmcnt(4)" ::: "memory");
            __builtin_amdgcn_sched_barrier(0);

            const unsigned short* Kc = &Ks[wid][0];

            // swapped QK^T: sc[row=kv local][col=q=l31]
            f32x16 sc = {};
            #pragma unroll
            for (int s = 0; s < 4; ++s) {
                int sl = (2 * s + hi) ^ (l31 & 7);
                bf16x8 kf = *reinterpret_cast<const bf16x8*>(Kc + l31 * 64 + sl * 8);
                sc = __builtin_amdgcn_mfma_f32_32x32x16_bf16(kf, qf[s], sc, 0, 0, 0);
            }

            // K ds_reads retired -> K buffer free: prefetch next K NOW
            asm volatile("s_waitcnt lgkmcnt(0)" ::: "memory");
            __builtin_amdgcn_sched_barrier(0);
            if (more) STAGE_K(kt + 4);   // covered by softmax+vf+PV below

            if (kt == qb) {   // diagonal tile: causal mask
                #pragma unroll
                for (int r = 0; r < 16; ++r) {
                    int kl = kt * 32 + (r & 3) + 8 * (r >> 2) + 4 * hi;
                    if (kl > q) sc[r] = -INFINITY;
                }
            }

            // static softmax (exp2 domain) -> packed bf16 P
            unsigned int g0, g1, g2, g3, g4, g5, g6, g7;
            float ps = 0.0f;
            {
                float e0, e1, e2, e3;
                e0=exp2f(sc[0]);  e1=exp2f(sc[1]);  e2=exp2f(sc[2]);  e3=exp2f(sc[3]);
                ps += (e0+e1)+(e2+e3); g0 = cvt_pk_bf16(e0,e1); g1 = cvt_pk_bf16(e2,e3);
                e0=exp2f(sc[4]);  e1=exp2f(sc[5]);  e2=exp2f(sc[6]);  e3=exp2f(sc[7]);
                ps += (e0+e1)+(e2+e3); g2 = cvt_pk_bf16(e0,e1); g3 = cvt_pk_bf16(e2,e3);
                e0=exp2f(sc[8]);  e1=exp2f(sc[9]);  e2=exp2f(sc[10]); e3=exp2f(sc[11]);
                ps += (e0+e1)+(e2+e3); g4 = cvt_pk_bf16(e0,e1); g5 = cvt_pk_bf16(e2,e3);
                e0=exp2f(sc[12]); e1=exp2f(sc[13]); e2=exp2f(sc[14]); e3=exp2f(sc[15]);
                ps += (e0+e1)+(e2+e3); g6 = cvt_pk_bf16(e0,e1); g7 = cvt_pk_bf16(e2,e3);
            }
            l += ps;

            // P -> A-fragments via permlane32_swap
            asm("v_permlane32_swap_b32 %0, %1" : "+v"(g0), "+v"(g2));
            asm("v_permlane32_swap_b32 %0, %1" : "+v"(g1), "+v"(g3));
            asm("v_permlane32_swap_b32 %0, %1" : "+v"(g4), "+v"(g6));
            asm("v_permlane32_swap_b32 %0, %1" : "+v"(g5), "+v"(g7));
            bf16x8 pa0 = __builtin_bit_cast(bf16x8, (u32x4){g0, g1, g2, g3});
            bf16x8 pa1 = __builtin_bit_cast(bf16x8, (u32x4){g4, g5, g6, g7});

            // V(cur) landed (K(next) may remain in flight)
            if (more) asm volatile("s_waitcnt vmcnt(4)" ::: "memory");
            else      asm volatile("s_waitcnt vmcnt(0)" ::: "memory");
            __builtin_amdgcn_sched_barrier(0);

            const unsigned short* Vc = &Vs[wid][0];
            bf16x8 vf[2][2];
            #pragma unroll
            for (int dt = 0; dt < 2; ++dt)
                #pragma unroll
                for (int s = 0; s < 2; ++s) {
                    int d = dt * 32 + l31;
                    int sl = (2 * s + hi) ^ ((d >> 1) & 3);
                    vf[dt][s] = *reinterpret_cast<const bf16x8*>(Vc + d * 32 + sl * 8);
                }

            // V ds_reads retired -> V buffer free: prefetch next V
            asm volatile("s_waitcnt lgkmcnt(0)" ::: "memory");
            __builtin_amdgcn_sched_barrier(0);
            if (more) STAGE_V(kt + 4);   // covered by PV + next QK + softmax

            // O += P · V   (pure MFMA cluster)
            __builtin_amdgcn_s_setprio(1);
            #pragma unroll
            for (int dt = 0; dt < 2; ++dt) {
                oacc[dt] = __builtin_amdgcn_mfma_f32_32x32x16_bf16(pa0, vf[dt][0], oacc[dt], 0, 0, 0);
                oacc[dt] = __builtin_amdgcn_mfma_f32_32x32x16_bf16(pa1, vf[dt][1], oacc[dt], 0, 0, 0);
            }
            __builtin_amdgcn_s_setprio(0);
        }
    }
#undef STAGE_K
#undef STAGE_V

    // ---- split-K combine: two phases reusing the 4KB per-wave buffers ----
    float* Olw = (float*)&Ks[wid][0];          // 32q x 32d f32 = 4KB
    float* Lpw = (float*)&Vs[wid][0];          // 32 f32
    float lc = l + __shfl_xor(l, 32, 64);
    if (hi == 0) Lpw[l31] = lc;

    const int cq = tid >> 3;
    const int cd = (tid & 7) * 4;
    float inv = 0.0f;
    #pragma unroll
    for (int ph = 0; ph < 2; ++ph) {
        __syncthreads();                       // prior reads of Ks/Vs complete
        #pragma unroll
        for (int r = 0; r < 16; ++r) {
            int qr = (r & 3) + 8 * (r >> 2) + 4 * hi;
            Olw[qr * 32 + l31] = oacc[ph][r];
        }
        __syncthreads();
        float s0 = 0, s1 = 0, s2 = 0, s3 = 0, lt = 0;
        #pragma unroll
        for (int w = 0; w < 4; ++w) {
            const float* O = (const float*)&Ks[w][0];
            f32x4 a = *reinterpret_cast<const f32x4*>(O + cq * 32 + cd);
            s0 += a[0]; s1 += a[1]; s2 += a[2]; s3 += a[3];
            if (ph == 0) lt += ((const float*)&Vs[w][0])[cq];
        }
        if (ph == 0) inv = 1.0f / lt;
        unsigned short o[4];
        o[0] = f2bf(s0 * inv); o[1] = f2bf(s1 * inv);
        o[2] = f2bf(s2 * inv); o[3] = f2bf(s3 * inv);
        *reinterpret_cast<uint2*>(
            Ctx + (baseRow + qw + cq) * D_ + h * HD_ + ph * 32 + cd) =
            *reinterpret_cast<const uint2*>(o);
    }
}

// ---- launch -----------------------------------------------------------------

extern "C" void kernel_launch(void* const* d_in, const int* in_sizes, int n_in,
                              void* d_out, int out_size, void* d_ws, size_t ws_size,
                              hipStream_t stream) {
    const float* x  = (const float*)d_in[0];
    const float* wq = (const float*)d_in[1];
    const float* wk = (const float*)d_in[2];
    const float* wv = (const float*)d_in[3];
    const float* wo = (const float*)d_in[4];
    const float* bo = (const float*)d_in[5];

    unsigned short* ws = (unsigned short*)d_ws;
    unsigned short* xb  = ws;                       // [4096][1024]  8 MB
    unsigned short* wqb = xb  + 4194304;            // wq|wk|wv stacked
    unsigned short* wob = wqb + 3145728;
    unsigned short* QKb = wob + 1048576;            // [4096][2048] 16 MB
    unsigned short* VT  = QKb + 8388608;            // [1024][4096]  8 MB
    unsigned short* Cx  = VT  + 4194304;            // [4096][1024]  8 MB

    cast_all<<<4096, 256, 0, stream>>>(x, wq, wk, wv, wo, xb);

    // merged QKV projection (V written transposed), XCD-chunked 1D grid
    gemm_qkv<<<768, 256, 0, stream>>>(xb, wqb, QKb, VT);

    // causal flash attention, split-K over 4 waves (round-12 structure)
    attn_kernel<<<2048, 256, 0, stream>>>(QKb, VT, Cx);

    // out = ctx @ Wo^T + b_out  (fp32 out), 128x64 tiles, XCD-chunked
    gemm_out<<<512, 256, 0, stream>>>(Cx, wob, (float*)d_out, bo);
}

// Round 15
// 98.578 us; speedup vs baseline: 1.4347x; 1.0438x over previous
//
#include <hip/hip_runtime.h>
#include <stdint.h>

// Problem constants
#define B_  2
#define S_  2048
#define D_  1024
#define H_  16
#define HD_ 64
#define M_  (B_*S_)   // 4096 rows

typedef __attribute__((ext_vector_type(8)))  short bf16x8;   // 8 bf16 in 4 VGPRs
typedef __attribute__((ext_vector_type(4)))  float f32x4;
typedef __attribute__((ext_vector_type(16))) float f32x16;
typedef __attribute__((ext_vector_type(4)))  unsigned int u32x4;

// ---- helpers ----------------------------------------------------------------

__device__ __forceinline__ unsigned short f2bf(float f) {
    unsigned int u = __float_as_uint(f);
    unsigned int r = (u + 0x7fffu + ((u >> 16) & 1u)) >> 16;
    return (unsigned short)r;
}

__device__ __forceinline__ unsigned int cvt_pk_bf16(float lo, float hi) {
    unsigned int r;
    asm("v_cvt_pk_bf16_f32 %0, %1, %2" : "=v"(r) : "v"(lo), "v"(hi));
    return r;
}

__device__ __forceinline__ void gload_lds16(const void* g, void* l) {
    __builtin_amdgcn_global_load_lds(
        (const __attribute__((address_space(1))) unsigned int*)g,
        (__attribute__((address_space(3))) unsigned int*)l,
        16, 0, 0);
}

// ---- fused fp32 -> bf16 cast; Wq/Wk pre-scaled by sqrt(log2(e)/8) -----------

__global__ __launch_bounds__(256) void cast_all(
    const float* __restrict__ x,
    const float* __restrict__ wq, const float* __restrict__ wk,
    const float* __restrict__ wv, const float* __restrict__ wo,
    unsigned short* __restrict__ dst)
{
    int b = blockIdx.x;
    const float* src;
    size_t soff, doff;
    float sc = 1.0f;
    if (b < 2048) {
        src = x; soff = (size_t)b * 2048; doff = soff;
    } else {
        int r  = (b - 2048) >> 9;
        int lb = (b - 2048) & 511;
        src = (r == 0) ? wq : (r == 1) ? wk : (r == 2) ? wv : wo;
        if (r <= 1) sc = 0.4246609093670877f;   // sqrt(log2(e)/sqrt(64))
        soff = (size_t)lb * 2048;
        doff = (size_t)4194304 + (size_t)r * 1048576 + soff;
    }
    int idx = threadIdx.x * 8;
    float4 a = *reinterpret_cast<const float4*>(src + soff + idx);
    float4 c = *reinterpret_cast<const float4*>(src + soff + idx + 4);
    unsigned short t[8];
    t[0]=f2bf(a.x*sc); t[1]=f2bf(a.y*sc); t[2]=f2bf(a.z*sc); t[3]=f2bf(a.w*sc);
    t[4]=f2bf(c.x*sc); t[5]=f2bf(c.y*sc); t[6]=f2bf(c.z*sc); t[7]=f2bf(c.w*sc);
    *reinterpret_cast<uint4*>(dst + doff + idx) = *reinterpret_cast<const uint4*>(t);
}

// ---- merged QKV projection: [4096][3072] = x @ [Wq;Wk;Wv]^T -----------------
// BK=64 (16 K-steps, half the barrier drains) + T2 XOR swizzle: LDS[row][slot]
// holds global[row][slot^(row&7)] (16B slots, 128B rows) — linear gload dest,
// pre-swizzled source, swizzled read => ds_read_b128 ~conflict-free (was 8-way).

__global__ __launch_bounds__(256) void gemm_qkv(
    const unsigned short* __restrict__ A,
    const unsigned short* __restrict__ Bm,
    unsigned short* __restrict__ Cqk,
    unsigned short* __restrict__ Vt)
{
    constexpr int BK = 64, K = 1024;
    __shared__ unsigned short As[128 * BK];   // 16 KB
    __shared__ unsigned short Bs[128 * BK];   // 16 KB

    const int tid  = threadIdx.x;
    const int lane = tid & 63;
    const int wid  = tid >> 6;
    const int wr = wid >> 1, wc = wid & 1;
    const int l15 = lane & 15, lhi = lane >> 4;

    const int lin  = blockIdx.x;                 // 0..767 (XCD-chunked)
    const int wgid = (lin & 7) * 96 + (lin >> 3);
    const int tm = (wgid / 24) * 128, tn = (wgid % 24) * 128;

    f32x4 acc[4][4] = {};

    const int srow8 = lane >> 3;                 // row-in-8-group
    const int scol  = ((lane & 7) ^ srow8) * 8;  // pre-swizzled source col (elems)

    for (int k0 = 0; k0 < K; k0 += BK) {
        __syncthreads();
        #pragma unroll
        for (int i = 0; i < 4; ++i) {
            int row = i * 32 + wid * 8 + srow8;
            gload_lds16(A  + (size_t)(tm + row) * K + k0 + scol,
                        (void*)(As + i * 2048 + wid * 512));
            gload_lds16(Bm + (size_t)(tn + row) * K + k0 + scol,
                        (void*)(Bs + i * 2048 + wid * 512));
        }
        __syncthreads();

        #pragma unroll
        for (int kk = 0; kk < 2; ++kk) {
            bf16x8 af[4], bfr[4];
            #pragma unroll
            for (int i = 0; i < 4; ++i) {
                int r = wr * 64 + i * 16 + l15;
                af[i] = *reinterpret_cast<const bf16x8*>(
                    As + r * BK + (((kk * 4 + lhi) ^ (r & 7)) * 8));
            }
            #pragma unroll
            for (int j = 0; j < 4; ++j) {
                int r = wc * 64 + j * 16 + l15;
                bfr[j] = *reinterpret_cast<const bf16x8*>(
                    Bs + r * BK + (((kk * 4 + lhi) ^ (r & 7)) * 8));
            }
            #pragma unroll
            for (int i = 0; i < 4; ++i)
                #pragma unroll
                for (int j = 0; j < 4; ++j)
                    acc[i][j] = __builtin_amdgcn_mfma_f32_16x16x32_bf16(af[i], bfr[j], acc[i][j], 0, 0, 0);
        }
    }

    const bool isV = (tn >= 2048);
    #pragma unroll
    for (int i = 0; i < 4; ++i) {
        #pragma unroll
        for (int j = 0; j < 4; ++j) {
            int col = tn + wc * 64 + j * 16 + l15;
            int row0 = tm + wr * 64 + i * 16 + lhi * 4;
            if (!isV) {
                #pragma unroll
                for (int r = 0; r < 4; ++r)
                    Cqk[(size_t)(row0 + r) * 2048 + col] = f2bf(acc[i][j][r]);
            } else {
                unsigned short t[4];
                #pragma unroll
                for (int r = 0; r < 4; ++r) t[r] = f2bf(acc[i][j][r]);
                *reinterpret_cast<uint2*>(Vt + (size_t)(col - 2048) * M_ + row0) =
                    *reinterpret_cast<const uint2*>(t);
            }
        }
    }
}

// ---- out-projection GEMM: [4096][1024] = Cx @ Wo^T + b, 128x64 tiles --------
// BK=64 + T2 swizzle (same scheme). LDS 24 KB.

__global__ __launch_bounds__(256) void gemm_out(
    const unsigned short* __restrict__ A,
    const unsigned short* __restrict__ Bm,
    float* __restrict__ C,
    const float* __restrict__ bias)
{
    constexpr int BK = 64, K = 1024, N = 1024;
    __shared__ unsigned short As[128 * BK];   // 16 KB
    __shared__ unsigned short Bs[64 * BK];    //  8 KB

    const int tid  = threadIdx.x;
    const int lane = tid & 63;
    const int wid  = tid >> 6;
    const int wr = wid >> 1, wc = wid & 1;
    const int l15 = lane & 15, lhi = lane >> 4;

    const int lin  = blockIdx.x;                 // 0..511 (XCD-chunked)
    const int wgid = (lin & 7) * 64 + (lin >> 3);
    const int tm = (wgid >> 4) * 128, tn = (wgid & 15) * 64;

    f32x4 acc[4][2] = {};

    const int srow8 = lane >> 3;
    const int scol  = ((lane & 7) ^ srow8) * 8;

    for (int k0 = 0; k0 < K; k0 += BK) {
        __syncthreads();
        #pragma unroll
        for (int i = 0; i < 4; ++i) {
            int row = i * 32 + wid * 8 + srow8;
            gload_lds16(A + (size_t)(tm + row) * K + k0 + scol,
                        (void*)(As + i * 2048 + wid * 512));
        }
        #pragma unroll
        for (int i = 0; i < 2; ++i) {
            int row = i * 32 + wid * 8 + srow8;
            gload_lds16(Bm + (size_t)(tn + row) * K + k0 + scol,
                        (void*)(Bs + i * 2048 + wid * 512));
        }
        __syncthreads();

        #pragma unroll
        for (int kk = 0; kk < 2; ++kk) {
            bf16x8 af[4], bfr[2];
            #pragma unroll
            for (int i = 0; i < 4; ++i) {
                int r = wr * 64 + i * 16 + l15;
                af[i] = *reinterpret_cast<const bf16x8*>(
                    As + r * BK + (((kk * 4 + lhi) ^ (r & 7)) * 8));
            }
            #pragma unroll
            for (int j = 0; j < 2; ++j) {
                int r = wc * 32 + j * 16 + l15;
                bfr[j] = *reinterpret_cast<const bf16x8*>(
                    Bs + r * BK + (((kk * 4 + lhi) ^ (r & 7)) * 8));
            }
            #pragma unroll
            for (int i = 0; i < 4; ++i)
                #pragma unroll
                for (int j = 0; j < 2; ++j)
                    acc[i][j] = __builtin_amdgcn_mfma_f32_16x16x32_bf16(af[i], bfr[j], acc[i][j], 0, 0, 0);
        }
    }

    #pragma unroll
    for (int i = 0; i < 4; ++i) {
        #pragma unroll
        for (int j = 0; j < 2; ++j) {
            int col = tn + wc * 32 + j * 16 + l15;
            float bv = bias[col];
            #pragma unroll
            for (int r = 0; r < 4; ++r) {
                int row = tm + wr * 64 + i * 16 + lhi * 4 + r;
                C[(size_t)row * N + col] = acc[i][j][r] + bv;
            }
        }
    }
}

// ---- flash attention (causal), split-K, single-buffer software pipeline -----
// (round-12 structure, measured 40.0-40.3 us — unchanged this round)

__global__ __launch_bounds__(256, 4) void attn_kernel(
    const unsigned short* __restrict__ QK,
    const unsigned short* __restrict__ VT,
    unsigned short* __restrict__ Ctx)
{
    __shared__ unsigned short Ks[4][32 * 64];  // per-wave [kv][d], swz ^(row&7)
    __shared__ unsigned short Vs[4][64 * 32];  // per-wave [d][kv], swz ^((d>>1)&3)

    const int tid  = threadIdx.x;
    const int lane = tid & 63;
    const int wid  = tid >> 6;          // 0..3
    const int l31  = lane & 31;
    const int hi   = lane >> 5;

    // XCD-aware remap (lin%8 = XCD); heavy q-blocks first
    const int lin  = blockIdx.x;
    const int idx  = lin >> 3;          // 0..255
    const int bh   = (lin & 7) + 8 * (idx & 3);
    const int qb   = 63 - (idx >> 2);   // 0..63, heavy first
    const int b = bh >> 4, h = bh & 15;
    const size_t baseRow = (size_t)b * S_;
    const int qw = qb * 32;
    const int q  = qw + l31;

    // Q B-fragments (same 32 q rows for all 4 waves; pre-scaled at cast)
    bf16x8 qf[4];
    #pragma unroll
    for (int s = 0; s < 4; ++s)
        qf[s] = *reinterpret_cast<const bf16x8*>(
            QK + (baseRow + q) * 2048 + h * HD_ + s * 16 + hi * 8);

    float l = 0.0f;
    f32x16 oacc[2] = {};

    const int nkt = qb + 1;             // KV tiles of 32

    // staging indices (per-wave lane)
    const int kr  = lane >> 3;          // K: row-in-8-group
    const int ks  = lane & 7;           // K: 16B slot (8 per 128B row)
    const int vr  = lane >> 2;          // V: row-in-16-group
    const int vsl = lane & 3;           // V: 16B slot (4 per 64B row)

#define STAGE_K(kt_) do {                                                      \
    int k0_ = (kt_) * 32;                                                      \
    _Pragma("unroll")                                                          \
    for (int i_ = 0; i_ < 4; ++i_) {                                           \
        int krow_ = i_ * 8 + kr;                                               \
        int ksc_  = (ks ^ kr) * 8;                                             \
        gload_lds16(QK + (baseRow + k0_ + krow_) * 2048 + D_ + h * HD_ + ksc_, \
                    (void*)(&Ks[wid][i_ * 512]));                              \
    } } while (0)
#define STAGE_V(kt_) do {                                                      \
    int k0_ = (kt_) * 32;                                                      \
    _Pragma("unroll")                                                          \
    for (int i_ = 0; i_ < 4; ++i_) {                                           \
        int vrow_ = i_ * 16 + vr;                                              \
        int vsc_  = (vsl ^ ((vrow_ >> 1) & 3)) * 8;                            \
        gload_lds16(VT + (size_t)(h * HD_ + vrow_) * M_ + baseRow + k0_ + vsc_,\
                    (void*)(&Vs[wid][i_ * 512]));                              \
    } } while (0)

    if (wid < nkt) {
        STAGE_K(wid);                    // prologue: first tile in flight
        STAGE_V(wid);
        for (int kt = wid; kt < nkt; kt += 4) {
            const bool more = (kt + 4 < nkt);

            // K(cur) landed (V(cur) still in flight)
            asm volatile("s_waitcnt vmcnt(4)" ::: "memory");
            __builtin_amdgcn_sched_barrier(0);

            const unsigned short* Kc = &Ks[wid][0];

            // swapped QK^T: sc[row=kv local][col=q=l31]
            f32x16 sc = {};
            #pragma unroll
            for (int s = 0; s < 4; ++s) {
                int sl = (2 * s + hi) ^ (l31 & 7);
                bf16x8 kf = *reinterpret_cast<const bf16x8*>(Kc + l31 * 64 + sl * 8);
                sc = __builtin_amdgcn_mfma_f32_32x32x16_bf16(kf, qf[s], sc, 0, 0, 0);
            }

            // K ds_reads retired -> K buffer free: prefetch next K NOW
            asm volatile("s_waitcnt lgkmcnt(0)" ::: "memory");
            __builtin_amdgcn_sched_barrier(0);
            if (more) STAGE_K(kt + 4);   // covered by softmax+vf+PV below

            if (kt == qb) {   // diagonal tile: causal mask
                #pragma unroll
                for (int r = 0; r < 16; ++r) {
                    int kl = kt * 32 + (r & 3) + 8 * (r >> 2) + 4 * hi;
                    if (kl > q) sc[r] = -INFINITY;
                }
            }

            // static softmax (exp2 domain) -> packed bf16 P
            unsigned int g0, g1, g2, g3, g4, g5, g6, g7;
            float ps = 0.0f;
            {
                float e0, e1, e2, e3;
                e0=exp2f(sc[0]);  e1=exp2f(sc[1]);  e2=exp2f(sc[2]);  e3=exp2f(sc[3]);
                ps += (e0+e1)+(e2+e3); g0 = cvt_pk_bf16(e0,e1); g1 = cvt_pk_bf16(e2,e3);
                e0=exp2f(sc[4]);  e1=exp2f(sc[5]);  e2=exp2f(sc[6]);  e3=exp2f(sc[7]);
                ps += (e0+e1)+(e2+e3); g2 = cvt_pk_bf16(e0,e1); g3 = cvt_pk_bf16(e2,e3);
                e0=exp2f(sc[8]);  e1=exp2f(sc[9]);  e2=exp2f(sc[10]); e3=exp2f(sc[11]);
                ps += (e0+e1)+(e2+e3); g4 = cvt_pk_bf16(e0,e1); g5 = cvt_pk_bf16(e2,e3);
                e0=exp2f(sc[12]); e1=exp2f(sc[13]); e2=exp2f(sc[14]); e3=exp2f(sc[15]);
                ps += (e0+e1)+(e2+e3); g6 = cvt_pk_bf16(e0,e1); g7 = cvt_pk_bf16(e2,e3);
            }
            l += ps;

            // P -> A-fragments via permlane32_swap
            asm("v_permlane32_swap_b32 %0, %1" : "+v"(g0), "+v"(g2));
            asm("v_permlane32_swap_b32 %0, %1" : "+v"(g1), "+v"(g3));
            asm("v_permlane32_swap_b32 %0, %1" : "+v"(g4), "+v"(g6));
            asm("v_permlane32_swap_b32 %0, %1" : "+v"(g5), "+v"(g7));
            bf16x8 pa0 = __builtin_bit_cast(bf16x8, (u32x4){g0, g1, g2, g3});
            bf16x8 pa1 = __builtin_bit_cast(bf16x8, (u32x4){g4, g5, g6, g7});

            // V(cur) landed (K(next) may remain in flight)
            if (more) asm volatile("s_waitcnt vmcnt(4)" ::: "memory");
            else      asm volatile("s_waitcnt vmcnt(0)" ::: "memory");
            __builtin_amdgcn_sched_barrier(0);

            const unsigned short* Vc = &Vs[wid][0];
            bf16x8 vf[2][2];
            #pragma unroll
            for (int dt = 0; dt < 2; ++dt)
                #pragma unroll
                for (int s = 0; s < 2; ++s) {
                    int d = dt * 32 + l31;
                    int sl = (2 * s + hi) ^ ((d >> 1) & 3);
                    vf[dt][s] = *reinterpret_cast<const bf16x8*>(Vc + d * 32 + sl * 8);
                }

            // V ds_reads retired -> V buffer free: prefetch next V
            asm volatile("s_waitcnt lgkmcnt(0)" ::: "memory");
            __builtin_amdgcn_sched_barrier(0);
            if (more) STAGE_V(kt + 4);   // covered by PV + next QK + softmax

            // O += P · V   (pure MFMA cluster)
            __builtin_amdgcn_s_setprio(1);
            #pragma unroll
            for (int dt = 0; dt < 2; ++dt) {
                oacc[dt] = __builtin_amdgcn_mfma_f32_32x32x16_bf16(pa0, vf[dt][0], oacc[dt], 0, 0, 0);
                oacc[dt] = __builtin_amdgcn_mfma_f32_32x32x16_bf16(pa1, vf[dt][1], oacc[dt], 0, 0, 0);
            }
            __builtin_amdgcn_s_setprio(0);
        }
    }
#undef STAGE_K
#undef STAGE_V

    // ---- split-K combine: two phases reusing the 4KB per-wave buffers ----
    float* Olw = (float*)&Ks[wid][0];          // 32q x 32d f32 = 4KB
    float* Lpw = (float*)&Vs[wid][0];          // 32 f32
    float lc = l + __shfl_xor(l, 32, 64);
    if (hi == 0) Lpw[l31] = lc;

    const int cq = tid >> 3;
    const int cd = (tid & 7) * 4;
    float inv = 0.0f;
    #pragma unroll
    for (int ph = 0; ph < 2; ++ph) {
        __syncthreads();                       // prior reads of Ks/Vs complete
        #pragma unroll
        for (int r = 0; r < 16; ++r) {
            int qr = (r & 3) + 8 * (r >> 2) + 4 * hi;
            Olw[qr * 32 + l31] = oacc[ph][r];
        }
        __syncthreads();
        float s0 = 0, s1 = 0, s2 = 0, s3 = 0, lt = 0;
        #pragma unroll
        for (int w = 0; w < 4; ++w) {
            const float* O = (const float*)&Ks[w][0];
            f32x4 a = *reinterpret_cast<const f32x4*>(O + cq * 32 + cd);
            s0 += a[0]; s1 += a[1]; s2 += a[2]; s3 += a[3];
            if (ph == 0) lt += ((const float*)&Vs[w][0])[cq];
        }
        if (ph == 0) inv = 1.0f / lt;
        unsigned short o[4];
        o[0] = f2bf(s0 * inv); o[1] = f2bf(s1 * inv);
        o[2] = f2bf(s2 * inv); o[3] = f2bf(s3 * inv);
        *reinterpret_cast<uint2*>(
            Ctx + (baseRow + qw + cq) * D_ + h * HD_ + ph * 32 + cd) =
            *reinterpret_cast<const uint2*>(o);
    }
}

// ---- launch -----------------------------------------------------------------

extern "C" void kernel_launch(void* const* d_in, const int* in_sizes, int n_in,
                              void* d_out, int out_size, void* d_ws, size_t ws_size,
                              hipStream_t stream) {
    const float* x  = (const float*)d_in[0];
    const float* wq = (const float*)d_in[1];
    const float* wk = (const float*)d_in[2];
    const float* wv = (const float*)d_in[3];
    const float* wo = (const float*)d_in[4];
    const float* bo = (const float*)d_in[5];

    unsigned short* ws = (unsigned short*)d_ws;
    unsigned short* xb  = ws;                       // [4096][1024]  8 MB
    unsigned short* wqb = xb  + 4194304;            // wq|wk|wv stacked
    unsigned short* wob = wqb + 3145728;
    unsigned short* QKb = wob + 1048576;            // [4096][2048] 16 MB
    unsigned short* VT  = QKb + 8388608;            // [1024][4096]  8 MB
    unsigned short* Cx  = VT  + 4194304;            // [4096][1024]  8 MB

    cast_all<<<4096, 256, 0, stream>>>(x, wq, wk, wv, wo, xb);

    // merged QKV projection (V written transposed), BK=64 + T2 swizzle
    gemm_qkv<<<768, 256, 0, stream>>>(xb, wqb, QKb, VT);

    // causal flash attention, split-K over 4 waves (round-12 structure)
    attn_kernel<<<2048, 256, 0, stream>>>(QKb, VT, Cx);

    // out = ctx @ Wo^T + b_out  (fp32 out), 128x64 tiles, BK=64 + T2 swizzle
    gemm_out<<<512, 256, 0, stream>>>(Cx, wob, (float*)d_out, bo);
}

// Round 16
// 98.542 us; speedup vs baseline: 1.4352x; 1.0004x over previous
//
#include <hip/hip_runtime.h>
#include <stdint.h>

// Problem constants
#define B_  2
#define S_  2048
#define D_  1024
#define H_  16
#define HD_ 64
#define M_  (B_*S_)   // 4096 rows

typedef __attribute__((ext_vector_type(8)))  short bf16x8;   // 8 bf16 in 4 VGPRs
typedef __attribute__((ext_vector_type(4)))  float f32x4;
typedef __attribute__((ext_vector_type(16))) float f32x16;
typedef __attribute__((ext_vector_type(4)))  unsigned int u32x4;

// ---- helpers ----------------------------------------------------------------

__device__ __forceinline__ unsigned short f2bf(float f) {
    unsigned int u = __float_as_uint(f);
    unsigned int r = (u + 0x7fffu + ((u >> 16) & 1u)) >> 16;
    return (unsigned short)r;
}

__device__ __forceinline__ unsigned int cvt_pk_bf16(float lo, float hi) {
    unsigned int r;
    asm("v_cvt_pk_bf16_f32 %0, %1, %2" : "=v"(r) : "v"(lo), "v"(hi));
    return r;
}

__device__ __forceinline__ void gload_lds16(const void* g, void* l) {
    __builtin_amdgcn_global_load_lds(
        (const __attribute__((address_space(1))) unsigned int*)g,
        (__attribute__((address_space(3))) unsigned int*)l,
        16, 0, 0);
}

// ---- fused fp32 -> bf16 cast; Wq/Wk pre-scaled by sqrt(log2(e)/8) -----------

__global__ __launch_bounds__(256) void cast_all(
    const float* __restrict__ x,
    const float* __restrict__ wq, const float* __restrict__ wk,
    const float* __restrict__ wv, const float* __restrict__ wo,
    unsigned short* __restrict__ dst)
{
    int b = blockIdx.x;
    const float* src;
    size_t soff, doff;
    float sc = 1.0f;
    if (b < 2048) {
        src = x; soff = (size_t)b * 2048; doff = soff;
    } else {
        int r  = (b - 2048) >> 9;
        int lb = (b - 2048) & 511;
        src = (r == 0) ? wq : (r == 1) ? wk : (r == 2) ? wv : wo;
        if (r <= 1) sc = 0.4246609093670877f;   // sqrt(log2(e)/sqrt(64))
        soff = (size_t)lb * 2048;
        doff = (size_t)4194304 + (size_t)r * 1048576 + soff;
    }
    int idx = threadIdx.x * 8;
    float4 a = *reinterpret_cast<const float4*>(src + soff + idx);
    float4 c = *reinterpret_cast<const float4*>(src + soff + idx + 4);
    unsigned short t[8];
    t[0]=f2bf(a.x*sc); t[1]=f2bf(a.y*sc); t[2]=f2bf(a.z*sc); t[3]=f2bf(a.w*sc);
    t[4]=f2bf(c.x*sc); t[5]=f2bf(c.y*sc); t[6]=f2bf(c.z*sc); t[7]=f2bf(c.w*sc);
    *reinterpret_cast<uint4*>(dst + doff + idx) = *reinterpret_cast<const uint4*>(t);
}

// ---- merged QKV projection: [4096][3072] = x @ [Wq;Wk;Wv]^T -----------------
// BK=64 + T2 swizzle + 32x32x16 MFMA (129 vs 155 cyc issue per K-step; half
// the MFMA instructions). Fragment layout identical to the attn kernel's
// hardware-verified mapping: A[row=l&31][k=(l>>5)*8+j], D row=(reg&3)+
// 8*(reg>>2)+4*(l>>5), col=l&31.

__global__ __launch_bounds__(256) void gemm_qkv(
    const unsigned short* __restrict__ A,
    const unsigned short* __restrict__ Bm,
    unsigned short* __restrict__ Cqk,
    unsigned short* __restrict__ Vt)
{
    constexpr int BK = 64, K = 1024;
    __shared__ unsigned short As[128 * BK];   // 16 KB
    __shared__ unsigned short Bs[128 * BK];   // 16 KB

    const int tid  = threadIdx.x;
    const int lane = tid & 63;
    const int wid  = tid >> 6;
    const int wr = wid >> 1, wc = wid & 1;
    const int l31 = lane & 31, hi = lane >> 5;

    const int lin  = blockIdx.x;                 // 0..767 (XCD-chunked)
    const int wgid = (lin & 7) * 96 + (lin >> 3);
    const int tm = (wgid / 24) * 128, tn = (wgid % 24) * 128;

    f32x16 acc[2][2] = {};                       // [ar][br] 32x32 each

    const int srow8 = lane >> 3;                 // row-in-8-group
    const int scol  = ((lane & 7) ^ srow8) * 8;  // pre-swizzled source col (elems)

    for (int k0 = 0; k0 < K; k0 += BK) {
        __syncthreads();
        #pragma unroll
        for (int i = 0; i < 4; ++i) {
            int row = i * 32 + wid * 8 + srow8;
            gload_lds16(A  + (size_t)(tm + row) * K + k0 + scol,
                        (void*)(As + i * 2048 + wid * 512));
            gload_lds16(Bm + (size_t)(tn + row) * K + k0 + scol,
                        (void*)(Bs + i * 2048 + wid * 512));
        }
        __syncthreads();

        #pragma unroll
        for (int ks = 0; ks < 4; ++ks) {         // K=16 slices of BK=64
            bf16x8 af[2], bfr[2];
            #pragma unroll
            for (int ar = 0; ar < 2; ++ar) {
                int r = wr * 64 + ar * 32 + l31;
                af[ar] = *reinterpret_cast<const bf16x8*>(
                    As + r * BK + (((ks * 2 + hi) ^ (r & 7)) * 8));
            }
            #pragma unroll
            for (int br = 0; br < 2; ++br) {
                int r = wc * 64 + br * 32 + l31;
                bfr[br] = *reinterpret_cast<const bf16x8*>(
                    Bs + r * BK + (((ks * 2 + hi) ^ (r & 7)) * 8));
            }
            #pragma unroll
            for (int ar = 0; ar < 2; ++ar)
                #pragma unroll
                for (int br = 0; br < 2; ++br)
                    acc[ar][br] = __builtin_amdgcn_mfma_f32_32x32x16_bf16(
                        af[ar], bfr[br], acc[ar][br], 0, 0, 0);
        }
    }

    const bool isV = (tn >= 2048);
    #pragma unroll
    for (int ar = 0; ar < 2; ++ar) {
        #pragma unroll
        for (int br = 0; br < 2; ++br) {
            int col = tn + wc * 64 + br * 32 + l31;
            if (!isV) {
                #pragma unroll
                for (int g = 0; g < 4; ++g)
                    #pragma unroll
                    for (int r4 = 0; r4 < 4; ++r4) {
                        int row = tm + wr * 64 + ar * 32 + g * 8 + 4 * hi + r4;
                        Cqk[(size_t)row * 2048 + col] = f2bf(acc[ar][br][g * 4 + r4]);
                    }
            } else {
                #pragma unroll
                for (int g = 0; g < 4; ++g) {
                    unsigned short t[4];
                    #pragma unroll
                    for (int r4 = 0; r4 < 4; ++r4) t[r4] = f2bf(acc[ar][br][g * 4 + r4]);
                    int row0 = tm + wr * 64 + ar * 32 + g * 8 + 4 * hi;
                    *reinterpret_cast<uint2*>(Vt + (size_t)(col - 2048) * M_ + row0) =
                        *reinterpret_cast<const uint2*>(t);
                }
            }
        }
    }
}

// ---- out-projection GEMM: [4096][1024] = Cx @ Wo^T + b, 128x64 tiles --------
// BK=64 + T2 swizzle + 32x32x16 MFMA. Wave tile 64x32 = 2 accs.

__global__ __launch_bounds__(256) void gemm_out(
    const unsigned short* __restrict__ A,
    const unsigned short* __restrict__ Bm,
    float* __restrict__ C,
    const float* __restrict__ bias)
{
    constexpr int BK = 64, K = 1024, N = 1024;
    __shared__ unsigned short As[128 * BK];   // 16 KB
    __shared__ unsigned short Bs[64 * BK];    //  8 KB

    const int tid  = threadIdx.x;
    const int lane = tid & 63;
    const int wid  = tid >> 6;
    const int wr = wid >> 1, wc = wid & 1;
    const int l31 = lane & 31, hi = lane >> 5;

    const int lin  = blockIdx.x;                 // 0..511 (XCD-chunked)
    const int wgid = (lin & 7) * 64 + (lin >> 3);
    const int tm = (wgid >> 4) * 128, tn = (wgid & 15) * 64;

    f32x16 acc[2] = {};                          // [ar] 32x32 each

    const int srow8 = lane >> 3;
    const int scol  = ((lane & 7) ^ srow8) * 8;

    for (int k0 = 0; k0 < K; k0 += BK) {
        __syncthreads();
        #pragma unroll
        for (int i = 0; i < 4; ++i) {
            int row = i * 32 + wid * 8 + srow8;
            gload_lds16(A + (size_t)(tm + row) * K + k0 + scol,
                        (void*)(As + i * 2048 + wid * 512));
        }
        #pragma unroll
        for (int i = 0; i < 2; ++i) {
            int row = i * 32 + wid * 8 + srow8;
            gload_lds16(Bm + (size_t)(tn + row) * K + k0 + scol,
                        (void*)(Bs + i * 2048 + wid * 512));
        }
        __syncthreads();

        #pragma unroll
        for (int ks = 0; ks < 4; ++ks) {
            bf16x8 af[2], bfr;
            #pragma unroll
            for (int ar = 0; ar < 2; ++ar) {
                int r = wr * 64 + ar * 32 + l31;
                af[ar] = *reinterpret_cast<const bf16x8*>(
                    As + r * BK + (((ks * 2 + hi) ^ (r & 7)) * 8));
            }
            {
                int r = wc * 32 + l31;
                bfr = *reinterpret_cast<const bf16x8*>(
                    Bs + r * BK + (((ks * 2 + hi) ^ (r & 7)) * 8));
            }
            #pragma unroll
            for (int ar = 0; ar < 2; ++ar)
                acc[ar] = __builtin_amdgcn_mfma_f32_32x32x16_bf16(
                    af[ar], bfr, acc[ar], 0, 0, 0);
        }
    }

    {
        int col = tn + wc * 32 + l31;
        float bv = bias[col];
        #pragma unroll
        for (int ar = 0; ar < 2; ++ar)
            #pragma unroll
            for (int g = 0; g < 4; ++g)
                #pragma unroll
                for (int r4 = 0; r4 < 4; ++r4) {
                    int row = tm + wr * 64 + ar * 32 + g * 8 + 4 * hi + r4;
                    C[(size_t)row * N + col] = acc[ar][g * 4 + r4] + bv;
                }
    }
}

// ---- flash attention (causal), split-K, single-buffer software pipeline -----
// (round-12 structure; this round: post-vmcnt sched_barriers removed so VALU
// can float across the waits — "memory" clobber still orders all memory ops)

__global__ __launch_bounds__(256, 4) void attn_kernel(
    const unsigned short* __restrict__ QK,
    const unsigned short* __restrict__ VT,
    unsigned short* __restrict__ Ctx)
{
    __shared__ unsigned short Ks[4][32 * 64];  // per-wave [kv][d], swz ^(row&7)
    __shared__ unsigned short Vs[4][64 * 32];  // per-wave [d][kv], swz ^((d>>1)&3)

    const int tid  = threadIdx.x;
    const int lane = tid & 63;
    const int wid  = tid >> 6;          // 0..3
    const int l31  = lane & 31;
    const int hi   = lane >> 5;

    // XCD-aware remap (lin%8 = XCD); heavy q-blocks first
    const int lin  = blockIdx.x;
    const int idx  = lin >> 3;          // 0..255
    const int bh   = (lin & 7) + 8 * (idx & 3);
    const int qb   = 63 - (idx >> 2);   // 0..63, heavy first
    const int b = bh >> 4, h = bh & 15;
    const size_t baseRow = (size_t)b * S_;
    const int qw = qb * 32;
    const int q  = qw + l31;

    // Q B-fragments (same 32 q rows for all 4 waves; pre-scaled at cast)
    bf16x8 qf[4];
    #pragma unroll
    for (int s = 0; s < 4; ++s)
        qf[s] = *reinterpret_cast<const bf16x8*>(
            QK + (baseRow + q) * 2048 + h * HD_ + s * 16 + hi * 8);

    float l = 0.0f;
    f32x16 oacc[2] = {};

    const int nkt = qb + 1;             // KV tiles of 32

    // staging indices (per-wave lane)
    const int kr  = lane >> 3;          // K: row-in-8-group
    const int ks  = lane & 7;           // K: 16B slot (8 per 128B row)
    const int vr  = lane >> 2;          // V: row-in-16-group
    const int vsl = lane & 3;           // V: 16B slot (4 per 64B row)

#define STAGE_K(kt_) do {                                                      \
    int k0_ = (kt_) * 32;                                                      \
    _Pragma("unroll")                                                          \
    for (int i_ = 0; i_ < 4; ++i_) {                                           \
        int krow_ = i_ * 8 + kr;                                               \
        int ksc_  = (ks ^ kr) * 8;                                             \
        gload_lds16(QK + (baseRow + k0_ + krow_) * 2048 + D_ + h * HD_ + ksc_, \
                    (void*)(&Ks[wid][i_ * 512]));                              \
    } } while (0)
#define STAGE_V(kt_) do {                                                      \
    int k0_ = (kt_) * 32;                                                      \
    _Pragma("unroll")                                                          \
    for (int i_ = 0; i_ < 4; ++i_) {                                           \
        int vrow_ = i_ * 16 + vr;                                              \
        int vsc_  = (vsl ^ ((vrow_ >> 1) & 3)) * 8;                            \
        gload_lds16(VT + (size_t)(h * HD_ + vrow_) * M_ + baseRow + k0_ + vsc_,\
                    (void*)(&Vs[wid][i_ * 512]));                              \
    } } while (0)

    if (wid < nkt) {
        STAGE_K(wid);                    // prologue: first tile in flight
        STAGE_V(wid);
        for (int kt = wid; kt < nkt; kt += 4) {
            const bool more = (kt + 4 < nkt);

            // K(cur) landed (V(cur) still in flight)
            asm volatile("s_waitcnt vmcnt(4)" ::: "memory");

            const unsigned short* Kc = &Ks[wid][0];

            // swapped QK^T: sc[row=kv local][col=q=l31]
            f32x16 sc = {};
            #pragma unroll
            for (int s = 0; s < 4; ++s) {
                int sl = (2 * s + hi) ^ (l31 & 7);
                bf16x8 kf = *reinterpret_cast<const bf16x8*>(Kc + l31 * 64 + sl * 8);
                sc = __builtin_amdgcn_mfma_f32_32x32x16_bf16(kf, qf[s], sc, 0, 0, 0);
            }

            // K ds_reads retired -> K buffer free: prefetch next K NOW
            asm volatile("s_waitcnt lgkmcnt(0)" ::: "memory");
            __builtin_amdgcn_sched_barrier(0);
            if (more) STAGE_K(kt + 4);   // covered by softmax+vf+PV below

            if (kt == qb) {   // diagonal tile: causal mask
                #pragma unroll
                for (int r = 0; r < 16; ++r) {
                    int kl = kt * 32 + (r & 3) + 8 * (r >> 2) + 4 * hi;
                    if (kl > q) sc[r] = -INFINITY;
                }
            }

            // static softmax (exp2 domain) -> packed bf16 P
            unsigned int g0, g1, g2, g3, g4, g5, g6, g7;
            float ps = 0.0f;
            {
                float e0, e1, e2, e3;
                e0=exp2f(sc[0]);  e1=exp2f(sc[1]);  e2=exp2f(sc[2]);  e3=exp2f(sc[3]);
                ps += (e0+e1)+(e2+e3); g0 = cvt_pk_bf16(e0,e1); g1 = cvt_pk_bf16(e2,e3);
                e0=exp2f(sc[4]);  e1=exp2f(sc[5]);  e2=exp2f(sc[6]);  e3=exp2f(sc[7]);
                ps += (e0+e1)+(e2+e3); g2 = cvt_pk_bf16(e0,e1); g3 = cvt_pk_bf16(e2,e3);
                e0=exp2f(sc[8]);  e1=exp2f(sc[9]);  e2=exp2f(sc[10]); e3=exp2f(sc[11]);
                ps += (e0+e1)+(e2+e3); g4 = cvt_pk_bf16(e0,e1); g5 = cvt_pk_bf16(e2,e3);
                e0=exp2f(sc[12]); e1=exp2f(sc[13]); e2=exp2f(sc[14]); e3=exp2f(sc[15]);
                ps += (e0+e1)+(e2+e3); g6 = cvt_pk_bf16(e0,e1); g7 = cvt_pk_bf16(e2,e3);
            }
            l += ps;

            // P -> A-fragments via permlane32_swap
            asm("v_permlane32_swap_b32 %0, %1" : "+v"(g0), "+v"(g2));
            asm("v_permlane32_swap_b32 %0, %1" : "+v"(g1), "+v"(g3));
            asm("v_permlane32_swap_b32 %0, %1" : "+v"(g4), "+v"(g6));
            asm("v_permlane32_swap_b32 %0, %1" : "+v"(g5), "+v"(g7));
            bf16x8 pa0 = __builtin_bit_cast(bf16x8, (u32x4){g0, g1, g2, g3});
            bf16x8 pa1 = __builtin_bit_cast(bf16x8, (u32x4){g4, g5, g6, g7});

            // V(cur) landed (K(next) may remain in flight)
            if (more) asm volatile("s_waitcnt vmcnt(4)" ::: "memory");
            else      asm volatile("s_waitcnt vmcnt(0)" ::: "memory");

            const unsigned short* Vc = &Vs[wid][0];
            bf16x8 vf[2][2];
            #pragma unroll
            for (int dt = 0; dt < 2; ++dt)
                #pragma unroll
                for (int s = 0; s < 2; ++s) {
                    int d = dt * 32 + l31;
                    int sl = (2 * s + hi) ^ ((d >> 1) & 3);
                    vf[dt][s] = *reinterpret_cast<const bf16x8*>(Vc + d * 32 + sl * 8);
                }

            // V ds_reads retired -> V buffer free: prefetch next V
            asm volatile("s_waitcnt lgkmcnt(0)" ::: "memory");
            __builtin_amdgcn_sched_barrier(0);
            if (more) STAGE_V(kt + 4);   // covered by PV + next QK + softmax

            // O += P · V   (pure MFMA cluster)
            __builtin_amdgcn_s_setprio(1);
            #pragma unroll
            for (int dt = 0; dt < 2; ++dt) {
                oacc[dt] = __builtin_amdgcn_mfma_f32_32x32x16_bf16(pa0, vf[dt][0], oacc[dt], 0, 0, 0);
                oacc[dt] = __builtin_amdgcn_mfma_f32_32x32x16_bf16(pa1, vf[dt][1], oacc[dt], 0, 0, 0);
            }
            __builtin_amdgcn_s_setprio(0);
        }
    }
#undef STAGE_K
#undef STAGE_V

    // ---- split-K combine: two phases reusing the 4KB per-wave buffers ----
    float* Olw = (float*)&Ks[wid][0];          // 32q x 32d f32 = 4KB
    float* Lpw = (float*)&Vs[wid][0];          // 32 f32
    float lc = l + __shfl_xor(l, 32, 64);
    if (hi == 0) Lpw[l31] = lc;

    const int cq = tid >> 3;
    const int cd = (tid & 7) * 4;
    float inv = 0.0f;
    #pragma unroll
    for (int ph = 0; ph < 2; ++ph) {
        __syncthreads();                       // prior reads of Ks/Vs complete
        #pragma unroll
        for (int r = 0; r < 16; ++r) {
            int qr = (r & 3) + 8 * (r >> 2) + 4 * hi;
            Olw[qr * 32 + l31] = oacc[ph][r];
        }
        __syncthreads();
        float s0 = 0, s1 = 0, s2 = 0, s3 = 0, lt = 0;
        #pragma unroll
        for (int w = 0; w < 4; ++w) {
            const float* O = (const float*)&Ks[w][0];
            f32x4 a = *reinterpret_cast<const f32x4*>(O + cq * 32 + cd);
            s0 += a[0]; s1 += a[1]; s2 += a[2]; s3 += a[3];
            if (ph == 0) lt += ((const float*)&Vs[w][0])[cq];
        }
        if (ph == 0) inv = 1.0f / lt;
        unsigned short o[4];
        o[0] = f2bf(s0 * inv); o[1] = f2bf(s1 * inv);
        o[2] = f2bf(s2 * inv); o[3] = f2bf(s3 * inv);
        *reinterpret_cast<uint2*>(
            Ctx + (baseRow + qw + cq) * D_ + h * HD_ + ph * 32 + cd) =
            *reinterpret_cast<const uint2*>(o);
    }
}

// ---- launch -----------------------------------------------------------------

extern "C" void kernel_launch(void* const* d_in, const int* in_sizes, int n_in,
                              void* d_out, int out_size, void* d_ws, size_t ws_size,
                              hipStream_t stream) {
    const float* x  = (const float*)d_in[0];
    const float* wq = (const float*)d_in[1];
    const float* wk = (const float*)d_in[2];
    const float* wv = (const float*)d_in[3];
    const float* wo = (const float*)d_in[4];
    const float* bo = (const float*)d_in[5];

    unsigned short* ws = (unsigned short*)d_ws;
    unsigned short* xb  = ws;                       // [4096][1024]  8 MB
    unsigned short* wqb = xb  + 4194304;            // wq|wk|wv stacked
    unsigned short* wob = wqb + 3145728;
    unsigned short* QKb = wob + 1048576;            // [4096][2048] 16 MB
    unsigned short* VT  = QKb + 8388608;            // [1024][4096]  8 MB
    unsigned short* Cx  = VT  + 4194304;            // [4096][1024]  8 MB

    cast_all<<<4096, 256, 0, stream>>>(x, wq, wk, wv, wo, xb);

    // merged QKV projection (V written transposed), BK=64 + T2 + 32x32 MFMA
    gemm_qkv<<<768, 256, 0, stream>>>(xb, wqb, QKb, VT);

    // causal flash attention, split-K over 4 waves (round-12 structure)
    attn_kernel<<<2048, 256, 0, stream>>>(QKb, VT, Cx);

    // out = ctx @ Wo^T + b_out  (fp32 out), 128x64 tiles, 32x32 MFMA
    gemm_out<<<512, 256, 0, stream>>>(Cx, wob, (float*)d_out, bo);
}

// Round 17
// 96.602 us; speedup vs baseline: 1.4640x; 1.0201x over previous
//
#include <hip/hip_runtime.h>
#include <stdint.h>

// Problem constants
#define B_  2
#define S_  2048
#define D_  1024
#define H_  16
#define HD_ 64
#define M_  (B_*S_)   // 4096 rows

typedef __attribute__((ext_vector_type(8)))  short bf16x8;   // 8 bf16 in 4 VGPRs
typedef __attribute__((ext_vector_type(4)))  float f32x4;
typedef __attribute__((ext_vector_type(16))) float f32x16;
typedef __attribute__((ext_vector_type(4)))  unsigned int u32x4;

// ---- helpers ----------------------------------------------------------------

__device__ __forceinline__ unsigned short f2bf(float f) {
    unsigned int u = __float_as_uint(f);
    unsigned int r = (u + 0x7fffu + ((u >> 16) & 1u)) >> 16;
    return (unsigned short)r;
}

__device__ __forceinline__ unsigned int cvt_pk_bf16(float lo, float hi) {
    unsigned int r;
    asm("v_cvt_pk_bf16_f32 %0, %1, %2" : "=v"(r) : "v"(lo), "v"(hi));
    return r;
}

// native v_exp_f32 (2^x). Args here are bounded (~[-40,+4]) and exp2(-inf)=0,
// so the OCML range/denorm fixup that exp2f carries is pure overhead.
__device__ __forceinline__ float fexp2(float x) {
    float r;
    asm("v_exp_f32 %0, %1" : "=v"(r) : "v"(x));
    return r;
}

__device__ __forceinline__ void gload_lds16(const void* g, void* l) {
    __builtin_amdgcn_global_load_lds(
        (const __attribute__((address_space(1))) unsigned int*)g,
        (__attribute__((address_space(3))) unsigned int*)l,
        16, 0, 0);
}

// ---- fused fp32 -> bf16 cast; Wq/Wk pre-scaled by sqrt(log2(e)/8) -----------

__global__ __launch_bounds__(256) void cast_all(
    const float* __restrict__ x,
    const float* __restrict__ wq, const float* __restrict__ wk,
    const float* __restrict__ wv, const float* __restrict__ wo,
    unsigned short* __restrict__ dst)
{
    int b = blockIdx.x;
    const float* src;
    size_t soff, doff;
    float sc = 1.0f;
    if (b < 2048) {
        src = x; soff = (size_t)b * 2048; doff = soff;
    } else {
        int r  = (b - 2048) >> 9;
        int lb = (b - 2048) & 511;
        src = (r == 0) ? wq : (r == 1) ? wk : (r == 2) ? wv : wo;
        if (r <= 1) sc = 0.4246609093670877f;   // sqrt(log2(e)/sqrt(64))
        soff = (size_t)lb * 2048;
        doff = (size_t)4194304 + (size_t)r * 1048576 + soff;
    }
    int idx = threadIdx.x * 8;
    float4 a = *reinterpret_cast<const float4*>(src + soff + idx);
    float4 c = *reinterpret_cast<const float4*>(src + soff + idx + 4);
    unsigned short t[8];
    t[0]=f2bf(a.x*sc); t[1]=f2bf(a.y*sc); t[2]=f2bf(a.z*sc); t[3]=f2bf(a.w*sc);
    t[4]=f2bf(c.x*sc); t[5]=f2bf(c.y*sc); t[6]=f2bf(c.z*sc); t[7]=f2bf(c.w*sc);
    *reinterpret_cast<uint4*>(dst + doff + idx) = *reinterpret_cast<const uint4*>(t);
}

// ---- merged QKV projection: [4096][3072] = x @ [Wq;Wk;Wv]^T -----------------
// BK=64 + T2 swizzle + 32x32x16 MFMA.

__global__ __launch_bounds__(256) void gemm_qkv(
    const unsigned short* __restrict__ A,
    const unsigned short* __restrict__ Bm,
    unsigned short* __restrict__ Cqk,
    unsigned short* __restrict__ Vt)
{
    constexpr int BK = 64, K = 1024;
    __shared__ unsigned short As[128 * BK];   // 16 KB
    __shared__ unsigned short Bs[128 * BK];   // 16 KB

    const int tid  = threadIdx.x;
    const int lane = tid & 63;
    const int wid  = tid >> 6;
    const int wr = wid >> 1, wc = wid & 1;
    const int l31 = lane & 31, hi = lane >> 5;

    const int lin  = blockIdx.x;                 // 0..767 (XCD-chunked)
    const int wgid = (lin & 7) * 96 + (lin >> 3);
    const int tm = (wgid / 24) * 128, tn = (wgid % 24) * 128;

    f32x16 acc[2][2] = {};                       // [ar][br] 32x32 each

    const int srow8 = lane >> 3;                 // row-in-8-group
    const int scol  = ((lane & 7) ^ srow8) * 8;  // pre-swizzled source col (elems)

    for (int k0 = 0; k0 < K; k0 += BK) {
        __syncthreads();
        #pragma unroll
        for (int i = 0; i < 4; ++i) {
            int row = i * 32 + wid * 8 + srow8;
            gload_lds16(A  + (size_t)(tm + row) * K + k0 + scol,
                        (void*)(As + i * 2048 + wid * 512));
            gload_lds16(Bm + (size_t)(tn + row) * K + k0 + scol,
                        (void*)(Bs + i * 2048 + wid * 512));
        }
        __syncthreads();

        #pragma unroll
        for (int ks = 0; ks < 4; ++ks) {         // K=16 slices of BK=64
            bf16x8 af[2], bfr[2];
            #pragma unroll
            for (int ar = 0; ar < 2; ++ar) {
                int r = wr * 64 + ar * 32 + l31;
                af[ar] = *reinterpret_cast<const bf16x8*>(
                    As + r * BK + (((ks * 2 + hi) ^ (r & 7)) * 8));
            }
            #pragma unroll
            for (int br = 0; br < 2; ++br) {
                int r = wc * 64 + br * 32 + l31;
                bfr[br] = *reinterpret_cast<const bf16x8*>(
                    Bs + r * BK + (((ks * 2 + hi) ^ (r & 7)) * 8));
            }
            #pragma unroll
            for (int ar = 0; ar < 2; ++ar)
                #pragma unroll
                for (int br = 0; br < 2; ++br)
                    acc[ar][br] = __builtin_amdgcn_mfma_f32_32x32x16_bf16(
                        af[ar], bfr[br], acc[ar][br], 0, 0, 0);
        }
    }

    const bool isV = (tn >= 2048);
    #pragma unroll
    for (int ar = 0; ar < 2; ++ar) {
        #pragma unroll
        for (int br = 0; br < 2; ++br) {
            int col = tn + wc * 64 + br * 32 + l31;
            if (!isV) {
                #pragma unroll
                for (int g = 0; g < 4; ++g)
                    #pragma unroll
                    for (int r4 = 0; r4 < 4; ++r4) {
                        int row = tm + wr * 64 + ar * 32 + g * 8 + 4 * hi + r4;
                        Cqk[(size_t)row * 2048 + col] = f2bf(acc[ar][br][g * 4 + r4]);
                    }
            } else {
                #pragma unroll
                for (int g = 0; g < 4; ++g) {
                    unsigned short t[4];
                    #pragma unroll
                    for (int r4 = 0; r4 < 4; ++r4) t[r4] = f2bf(acc[ar][br][g * 4 + r4]);
                    int row0 = tm + wr * 64 + ar * 32 + g * 8 + 4 * hi;
                    *reinterpret_cast<uint2*>(Vt + (size_t)(col - 2048) * M_ + row0) =
                        *reinterpret_cast<const uint2*>(t);
                }
            }
        }
    }
}

// ---- out-projection GEMM: [4096][1024] = Cx @ Wo^T + b, 128x64 tiles --------
// BK=64 + T2 swizzle + 32x32x16 MFMA. Wave tile 64x32 = 2 accs.

__global__ __launch_bounds__(256) void gemm_out(
    const unsigned short* __restrict__ A,
    const unsigned short* __restrict__ Bm,
    float* __restrict__ C,
    const float* __restrict__ bias)
{
    constexpr int BK = 64, K = 1024, N = 1024;
    __shared__ unsigned short As[128 * BK];   // 16 KB
    __shared__ unsigned short Bs[64 * BK];    //  8 KB

    const int tid  = threadIdx.x;
    const int lane = tid & 63;
    const int wid  = tid >> 6;
    const int wr = wid >> 1, wc = wid & 1;
    const int l31 = lane & 31, hi = lane >> 5;

    const int lin  = blockIdx.x;                 // 0..511 (XCD-chunked)
    const int wgid = (lin & 7) * 64 + (lin >> 3);
    const int tm = (wgid >> 4) * 128, tn = (wgid & 15) * 64;

    f32x16 acc[2] = {};                          // [ar] 32x32 each

    const int srow8 = lane >> 3;
    const int scol  = ((lane & 7) ^ srow8) * 8;

    for (int k0 = 0; k0 < K; k0 += BK) {
        __syncthreads();
        #pragma unroll
        for (int i = 0; i < 4; ++i) {
            int row = i * 32 + wid * 8 + srow8;
            gload_lds16(A + (size_t)(tm + row) * K + k0 + scol,
                        (void*)(As + i * 2048 + wid * 512));
        }
        #pragma unroll
        for (int i = 0; i < 2; ++i) {
            int row = i * 32 + wid * 8 + srow8;
            gload_lds16(Bm + (size_t)(tn + row) * K + k0 + scol,
                        (void*)(Bs + i * 2048 + wid * 512));
        }
        __syncthreads();

        #pragma unroll
        for (int ks = 0; ks < 4; ++ks) {
            bf16x8 af[2], bfr;
            #pragma unroll
            for (int ar = 0; ar < 2; ++ar) {
                int r = wr * 64 + ar * 32 + l31;
                af[ar] = *reinterpret_cast<const bf16x8*>(
                    As + r * BK + (((ks * 2 + hi) ^ (r & 7)) * 8));
            }
            {
                int r = wc * 32 + l31;
                bfr = *reinterpret_cast<const bf16x8*>(
                    Bs + r * BK + (((ks * 2 + hi) ^ (r & 7)) * 8));
            }
            #pragma unroll
            for (int ar = 0; ar < 2; ++ar)
                acc[ar] = __builtin_amdgcn_mfma_f32_32x32x16_bf16(
                    af[ar], bfr, acc[ar], 0, 0, 0);
        }
    }

    {
        int col = tn + wc * 32 + l31;
        float bv = bias[col];
        #pragma unroll
        for (int ar = 0; ar < 2; ++ar)
            #pragma unroll
            for (int g = 0; g < 4; ++g)
                #pragma unroll
                for (int r4 = 0; r4 < 4; ++r4) {
                    int row = tm + wr * 64 + ar * 32 + g * 8 + 4 * hi + r4;
                    C[(size_t)row * N + col] = acc[ar][g * 4 + r4] + bv;
                }
    }
}

// ---- flash attention (causal), split-K, single-buffer software pipeline -----
// (round-12 structure; this round: exp2f -> native v_exp_f32)

__global__ __launch_bounds__(256, 4) void attn_kernel(
    const unsigned short* __restrict__ QK,
    const unsigned short* __restrict__ VT,
    unsigned short* __restrict__ Ctx)
{
    __shared__ unsigned short Ks[4][32 * 64];  // per-wave [kv][d], swz ^(row&7)
    __shared__ unsigned short Vs[4][64 * 32];  // per-wave [d][kv], swz ^((d>>1)&3)

    const int tid  = threadIdx.x;
    const int lane = tid & 63;
    const int wid  = tid >> 6;          // 0..3
    const int l31  = lane & 31;
    const int hi   = lane >> 5;

    // XCD-aware remap (lin%8 = XCD); heavy q-blocks first
    const int lin  = blockIdx.x;
    const int idx  = lin >> 3;          // 0..255
    const int bh   = (lin & 7) + 8 * (idx & 3);
    const int qb   = 63 - (idx >> 2);   // 0..63, heavy first
    const int b = bh >> 4, h = bh & 15;
    const size_t baseRow = (size_t)b * S_;
    const int qw = qb * 32;
    const int q  = qw + l31;

    // Q B-fragments (same 32 q rows for all 4 waves; pre-scaled at cast)
    bf16x8 qf[4];
    #pragma unroll
    for (int s = 0; s < 4; ++s)
        qf[s] = *reinterpret_cast<const bf16x8*>(
            QK + (baseRow + q) * 2048 + h * HD_ + s * 16 + hi * 8);

    float l = 0.0f;
    f32x16 oacc[2] = {};

    const int nkt = qb + 1;             // KV tiles of 32

    // staging indices (per-wave lane)
    const int kr  = lane >> 3;          // K: row-in-8-group
    const int ks  = lane & 7;           // K: 16B slot (8 per 128B row)
    const int vr  = lane >> 2;          // V: row-in-16-group
    const int vsl = lane & 3;           // V: 16B slot (4 per 64B row)

#define STAGE_K(kt_) do {                                                      \
    int k0_ = (kt_) * 32;                                                      \
    _Pragma("unroll")                                                          \
    for (int i_ = 0; i_ < 4; ++i_) {                                           \
        int krow_ = i_ * 8 + kr;                                               \
        int ksc_  = (ks ^ kr) * 8;                                             \
        gload_lds16(QK + (baseRow + k0_ + krow_) * 2048 + D_ + h * HD_ + ksc_, \
                    (void*)(&Ks[wid][i_ * 512]));                              \
    } } while (0)
#define STAGE_V(kt_) do {                                                      \
    int k0_ = (kt_) * 32;                                                      \
    _Pragma("unroll")                                                          \
    for (int i_ = 0; i_ < 4; ++i_) {                                           \
        int vrow_ = i_ * 16 + vr;                                              \
        int vsc_  = (vsl ^ ((vrow_ >> 1) & 3)) * 8;                            \
        gload_lds16(VT + (size_t)(h * HD_ + vrow_) * M_ + baseRow + k0_ + vsc_,\
                    (void*)(&Vs[wid][i_ * 512]));                              \
    } } while (0)

    if (wid < nkt) {
        STAGE_K(wid);                    // prologue: first tile in flight
        STAGE_V(wid);
        for (int kt = wid; kt < nkt; kt += 4) {
            const bool more = (kt + 4 < nkt);

            // K(cur) landed (V(cur) still in flight)
            asm volatile("s_waitcnt vmcnt(4)" ::: "memory");

            const unsigned short* Kc = &Ks[wid][0];

            // swapped QK^T: sc[row=kv local][col=q=l31]
            f32x16 sc = {};
            #pragma unroll
            for (int s = 0; s < 4; ++s) {
                int sl = (2 * s + hi) ^ (l31 & 7);
                bf16x8 kf = *reinterpret_cast<const bf16x8*>(Kc + l31 * 64 + sl * 8);
                sc = __builtin_amdgcn_mfma_f32_32x32x16_bf16(kf, qf[s], sc, 0, 0, 0);
            }

            // K ds_reads retired -> K buffer free: prefetch next K NOW
            asm volatile("s_waitcnt lgkmcnt(0)" ::: "memory");
            __builtin_amdgcn_sched_barrier(0);
            if (more) STAGE_K(kt + 4);   // covered by softmax+vf+PV below

            if (kt == qb) {   // diagonal tile: causal mask
                #pragma unroll
                for (int r = 0; r < 16; ++r) {
                    int kl = kt * 32 + (r & 3) + 8 * (r >> 2) + 4 * hi;
                    if (kl > q) sc[r] = -INFINITY;
                }
            }

            // static softmax (exp2 domain, native v_exp_f32) -> packed bf16 P
            unsigned int g0, g1, g2, g3, g4, g5, g6, g7;
            float ps = 0.0f;
            {
                float e0, e1, e2, e3;
                e0=fexp2(sc[0]);  e1=fexp2(sc[1]);  e2=fexp2(sc[2]);  e3=fexp2(sc[3]);
                ps += (e0+e1)+(e2+e3); g0 = cvt_pk_bf16(e0,e1); g1 = cvt_pk_bf16(e2,e3);
                e0=fexp2(sc[4]);  e1=fexp2(sc[5]);  e2=fexp2(sc[6]);  e3=fexp2(sc[7]);
                ps += (e0+e1)+(e2+e3); g2 = cvt_pk_bf16(e0,e1); g3 = cvt_pk_bf16(e2,e3);
                e0=fexp2(sc[8]);  e1=fexp2(sc[9]);  e2=fexp2(sc[10]); e3=fexp2(sc[11]);
                ps += (e0+e1)+(e2+e3); g4 = cvt_pk_bf16(e0,e1); g5 = cvt_pk_bf16(e2,e3);
                e0=fexp2(sc[12]); e1=fexp2(sc[13]); e2=fexp2(sc[14]); e3=fexp2(sc[15]);
                ps += (e0+e1)+(e2+e3); g6 = cvt_pk_bf16(e0,e1); g7 = cvt_pk_bf16(e2,e3);
            }
            l += ps;

            // P -> A-fragments via permlane32_swap
            asm("v_permlane32_swap_b32 %0, %1" : "+v"(g0), "+v"(g2));
            asm("v_permlane32_swap_b32 %0, %1" : "+v"(g1), "+v"(g3));
            asm("v_permlane32_swap_b32 %0, %1" : "+v"(g4), "+v"(g6));
            asm("v_permlane32_swap_b32 %0, %1" : "+v"(g5), "+v"(g7));
            bf16x8 pa0 = __builtin_bit_cast(bf16x8, (u32x4){g0, g1, g2, g3});
            bf16x8 pa1 = __builtin_bit_cast(bf16x8, (u32x4){g4, g5, g6, g7});

            // V(cur) landed (K(next) may remain in flight)
            if (more) asm volatile("s_waitcnt vmcnt(4)" ::: "memory");
            else      asm volatile("s_waitcnt vmcnt(0)" ::: "memory");

            const unsigned short* Vc = &Vs[wid][0];
            bf16x8 vf[2][2];
            #pragma unroll
            for (int dt = 0; dt < 2; ++dt)
                #pragma unroll
                for (int s = 0; s < 2; ++s) {
                    int d = dt * 32 + l31;
                    int sl = (2 * s + hi) ^ ((d >> 1) & 3);
                    vf[dt][s] = *reinterpret_cast<const bf16x8*>(Vc + d * 32 + sl * 8);
                }

            // V ds_reads retired -> V buffer free: prefetch next V
            asm volatile("s_waitcnt lgkmcnt(0)" ::: "memory");
            __builtin_amdgcn_sched_barrier(0);
            if (more) STAGE_V(kt + 4);   // covered by PV + next QK + softmax

            // O += P · V   (pure MFMA cluster)
            __builtin_amdgcn_s_setprio(1);
            #pragma unroll
            for (int dt = 0; dt < 2; ++dt) {
                oacc[dt] = __builtin_amdgcn_mfma_f32_32x32x16_bf16(pa0, vf[dt][0], oacc[dt], 0, 0, 0);
                oacc[dt] = __builtin_amdgcn_mfma_f32_32x32x16_bf16(pa1, vf[dt][1], oacc[dt], 0, 0, 0);
            }
            __builtin_amdgcn_s_setprio(0);
        }
    }
#undef STAGE_K
#undef STAGE_V

    // ---- split-K combine: two phases reusing the 4KB per-wave buffers ----
    float* Olw = (float*)&Ks[wid][0];          // 32q x 32d f32 = 4KB
    float* Lpw = (float*)&Vs[wid][0];          // 32 f32
    float lc = l + __shfl_xor(l, 32, 64);
    if (hi == 0) Lpw[l31] = lc;

    const int cq = tid >> 3;
    const int cd = (tid & 7) * 4;
    float inv = 0.0f;
    #pragma unroll
    for (int ph = 0; ph < 2; ++ph) {
        __syncthreads();                       // prior reads of Ks/Vs complete
        #pragma unroll
        for (int r = 0; r < 16; ++r) {
            int qr = (r & 3) + 8 * (r >> 2) + 4 * hi;
            Olw[qr * 32 + l31] = oacc[ph][r];
        }
        __syncthreads();
        float s0 = 0, s1 = 0, s2 = 0, s3 = 0, lt = 0;
        #pragma unroll
        for (int w = 0; w < 4; ++w) {
            const float* O = (const float*)&Ks[w][0];
            f32x4 a = *reinterpret_cast<const f32x4*>(O + cq * 32 + cd);
            s0 += a[0]; s1 += a[1]; s2 += a[2]; s3 += a[3];
            if (ph == 0) lt += ((const float*)&Vs[w][0])[cq];
        }
        if (ph == 0) inv = 1.0f / lt;
        unsigned short o[4];
        o[0] = f2bf(s0 * inv); o[1] = f2bf(s1 * inv);
        o[2] = f2bf(s2 * inv); o[3] = f2bf(s3 * inv);
        *reinterpret_cast<uint2*>(
            Ctx + (baseRow + qw + cq) * D_ + h * HD_ + ph * 32 + cd) =
            *reinterpret_cast<const uint2*>(o);
    }
}

// ---- launch -----------------------------------------------------------------

extern "C" void kernel_launch(void* const* d_in, const int* in_sizes, int n_in,
                              void* d_out, int out_size, void* d_ws, size_t ws_size,
                              hipStream_t stream) {
    const float* x  = (const float*)d_in[0];
    const float* wq = (const float*)d_in[1];
    const float* wk = (const float*)d_in[2];
    const float* wv = (const float*)d_in[3];
    const float* wo = (const float*)d_in[4];
    const float* bo = (const float*)d_in[5];

    unsigned short* ws = (unsigned short*)d_ws;
    unsigned short* xb  = ws;                       // [4096][1024]  8 MB
    unsigned short* wqb = xb  + 4194304;            // wq|wk|wv stacked
    unsigned short* wob = wqb + 3145728;
    unsigned short* QKb = wob + 1048576;            // [4096][2048] 16 MB
    unsigned short* VT  = QKb + 8388608;            // [1024][4096]  8 MB
    unsigned short* Cx  = VT  + 4194304;            // [4096][1024]  8 MB

    cast_all<<<4096, 256, 0, stream>>>(x, wq, wk, wv, wo, xb);

    // merged QKV projection (V written transposed), BK=64 + T2 + 32x32 MFMA
    gemm_qkv<<<768, 256, 0, stream>>>(xb, wqb, QKb, VT);

    // causal flash attention, split-K over 4 waves (native-exp2 softmax)
    attn_kernel<<<2048, 256, 0, stream>>>(QKb, VT, Cx);

    // out = ctx @ Wo^T + b_out  (fp32 out), 128x64 tiles, 32x32 MFMA
    gemm_out<<<512, 256, 0, stream>>>(Cx, wob, (float*)d_out, bo);
}